// Round 6
// baseline (176.333 us; speedup 1.0000x reference)
//
#include <hip/hip_runtime.h>
#include <math.h>

constexpr int B = 4;
constexpr int N = 16384;
constexpr int D = 256;
constexpr int M = 64;
constexpr int H = 8;
// HD = 32, 3D = 768

typedef __attribute__((ext_vector_type(8))) short short8;
typedef __attribute__((ext_vector_type(4))) float floatx4;

__device__ __forceinline__ float4 ld4(const float* p) {
  return *reinterpret_cast<const float4*>(p);
}
__device__ __forceinline__ unsigned short f2bf(float f) {
  unsigned u = __float_as_uint(f);
  unsigned r = (u + 0x7fffu + ((u >> 16) & 1u)) >> 16;  // RNE
  return (unsigned short)r;
}

// ---------------------------------------------------------------------------
// K0: one-time fp32 -> bf16 conversion of Ws (64x256), Wqkv (768x256),
// Wo (256x256); also zeroes denom, tokens, tokO. grid 136 x 256.
__global__ __launch_bounds__(256) void k0_prep(
    const float* __restrict__ Ws, const float* __restrict__ Wqkv,
    const float* __restrict__ Wo, unsigned short* __restrict__ WsB,
    unsigned short* __restrict__ WqkvB, unsigned short* __restrict__ WoB,
    float* __restrict__ denom, float* __restrict__ tokens,
    float* __restrict__ tokO) {
  const int g = blockIdx.x * 256 + threadIdx.x;
  if (g < 32768) {
    *reinterpret_cast<float2*>(&tokens[g * 2]) = make_float2(0.f, 0.f);
    *reinterpret_cast<float2*>(&tokO[g * 2]) = make_float2(0.f, 0.f);
  }
  if (g < 128)
    *reinterpret_cast<float2*>(&denom[g * 2]) = make_float2(0.f, 0.f);
  const float* src;
  unsigned short* dst;
  int off;
  if (g < 2048) {
    src = Ws; dst = WsB; off = g;
  } else if (g < 26624) {
    src = Wqkv; dst = WqkvB; off = g - 2048;
  } else {
    src = Wo; dst = WoB; off = g - 26624;
  }
  const float4 a = ld4(&src[(size_t)off * 8]);
  const float4 c = ld4(&src[(size_t)off * 8 + 4]);
  unsigned d0 = (unsigned)f2bf(a.x) | ((unsigned)f2bf(a.y) << 16);
  unsigned d1 = (unsigned)f2bf(a.z) | ((unsigned)f2bf(a.w) << 16);
  unsigned d2 = (unsigned)f2bf(c.x) | ((unsigned)f2bf(c.y) << 16);
  unsigned d3 = (unsigned)f2bf(c.z) | ((unsigned)f2bf(c.w) << 16);
  *reinterpret_cast<uint4*>(&dst[(size_t)off * 8]) = make_uint4(d0, d1, d2, d3);
}

// ---------------------------------------------------------------------------
// K12 (fused logits + exp + En + pooling): per 64-n subtile (2 per block):
//   - x rows -> regs (bulk ld4), logits MFMA vs staged Wt, exp -> En store +
//     denom partials (red LDS)
//   - scatter afr -> XsT[256][70] (x^T bf16; pad 70: 8-row-stride scalar
//     writes land on all 32 banks, 2-way u16-pair only) and ebf -> EsT[64][70]
//   - pooling MFMA: wave w owns m-tile w; A-frag = EsT[w*16+l15] b128,
//     B-frag = XsT[dt*16+l15] b128; acc2[16] accumulates across subtiles
//   - one atomic pass into tokens
// Replaces old k1 (x read) + k2 (second x read + restage + En re-read).
// LDS 77 KB -> 2 blocks/CU. grid (N/128, B), block 256 (4 waves).
__global__ __launch_bounds__(256, 2) void k12_fused(
    const float* __restrict__ x, const unsigned short* __restrict__ WsB,
    const float* __restrict__ bs, unsigned short* __restrict__ En,
    float* __restrict__ denom, float* __restrict__ tokens) {
  __shared__ unsigned short Wt[64][264];   // Ws [m][d] bf16 (33792 B)
  __shared__ unsigned short EsT[64][70];   // E^T [m][n-local] (8960 B)
  __shared__ unsigned short XsT[256][70];  // x^T [d][n-local] (35840 B)
  __shared__ float red[64];
  const int b = blockIdx.y;
  const int nb0 = blockIdx.x * 128;
  const int tid = threadIdx.x;
  const int w = tid >> 6, l = tid & 63;
  const int l15 = l & 15;
  const int q8 = (l >> 4) * 8;
  const int r4 = (l >> 4) * 4;
  const int ar = w * 16 + l15;  // this thread's n-row within 64-subtile

  // stage Ws once
#pragma unroll
  for (int p = 0; p < 8; ++p) {
    const int u = p * 256 + tid;
    const int row = u >> 5;
    const int c = (u & 31) * 8;
    *reinterpret_cast<short8*>(&Wt[row][c]) =
        *reinterpret_cast<const short8*>(&WsB[(size_t)row * 256 + c]);
  }
  if (tid < 64) red[tid] = 0.0f;
  __syncthreads();

  floatx4 acc2[16];
#pragma unroll
  for (int i = 0; i < 16; ++i) acc2[i] = {0.f, 0.f, 0.f, 0.f};

  for (int t = 0; t < 2; ++t) {
    const int n0 = nb0 + t * 64;
    // bulk-load this thread's x row slice
    float4 fx[16];
    const float* xrow = &x[((size_t)(b * N + n0 + ar)) * D];
#pragma unroll
    for (int ks = 0; ks < 8; ++ks) {
      fx[2 * ks] = ld4(&xrow[ks * 32 + q8]);
      fx[2 * ks + 1] = ld4(&xrow[ks * 32 + q8 + 4]);
    }
    short8 afr[8];
#pragma unroll
    for (int ks = 0; ks < 8; ++ks) {
      const float4 a0 = fx[2 * ks], a1 = fx[2 * ks + 1];
      short8 tt;
      tt[0] = (short)f2bf(a0.x); tt[1] = (short)f2bf(a0.y);
      tt[2] = (short)f2bf(a0.z); tt[3] = (short)f2bf(a0.w);
      tt[4] = (short)f2bf(a1.x); tt[5] = (short)f2bf(a1.y);
      tt[6] = (short)f2bf(a1.z); tt[7] = (short)f2bf(a1.w);
      afr[ks] = tt;
    }

    // logits MFMA: C[n, m] = sum_d x[n,d] * Ws[m,d]
    floatx4 acc[4] = {{0.f, 0.f, 0.f, 0.f},
                      {0.f, 0.f, 0.f, 0.f},
                      {0.f, 0.f, 0.f, 0.f},
                      {0.f, 0.f, 0.f, 0.f}};
#pragma unroll
    for (int ks = 0; ks < 8; ++ks) {
#pragma unroll
      for (int mt = 0; mt < 4; ++mt) {
        short8 bf = *reinterpret_cast<short8*>(&Wt[mt * 16 + l15][ks * 32 + q8]);
        acc[mt] =
            __builtin_amdgcn_mfma_f32_16x16x32_bf16(afr[ks], bf, acc[mt], 0, 0, 0);
      }
    }

    // exp + En stores + denom partials; keep bf16 E for EsT
    unsigned short ebf[16];
#pragma unroll
    for (int mt = 0; mt < 4; ++mt) {
      const int m = mt * 16 + l15;
      const float bsm = bs[m];
      float s = 0.0f;
#pragma unroll
      for (int r = 0; r < 4; ++r) {
        const int n = w * 16 + r4 + r;
        const float e = expf(acc[mt][r] + bsm);
        s += e;
        const unsigned short eb = f2bf(e);
        ebf[mt * 4 + r] = eb;
        En[((size_t)(b * N + n0 + n)) * M + m] = eb;
      }
      atomicAdd(&red[m], s);
    }

    __syncthreads();  // previous subtile's pooling reads complete
    // stage x^T and E^T
#pragma unroll
    for (int ks = 0; ks < 8; ++ks)
#pragma unroll
      for (int j = 0; j < 8; ++j)
        XsT[ks * 32 + q8 + j][ar] = (unsigned short)afr[ks][j];
#pragma unroll
    for (int mt = 0; mt < 4; ++mt)
#pragma unroll
      for (int r = 0; r < 4; ++r)
        EsT[mt * 16 + l15][w * 16 + r4 + r] = ebf[mt * 4 + r];
    __syncthreads();  // staging complete

    // pooling MFMA: C[m, d] += sum_n E[n,m] * x[n,d]; wave w owns m-tile w
#pragma unroll
    for (int ks = 0; ks < 2; ++ks) {
      const int nf = ks * 32 + q8;
      short8 a = *reinterpret_cast<short8*>(&EsT[w * 16 + l15][nf]);
#pragma unroll
      for (int dt4 = 0; dt4 < 16; ++dt4) {
        short8 bf = *reinterpret_cast<short8*>(&XsT[dt4 * 16 + l15][nf]);
        acc2[dt4] =
            __builtin_amdgcn_mfma_f32_16x16x32_bf16(a, bf, acc2[dt4], 0, 0, 0);
      }
    }
  }

  // denom flush (all red atomics are before the last in-loop barrier)
  if (tid < 64) atomicAdd(&denom[b * M + tid], red[tid]);
  // tokens partial flush: 64 atomics/thread, distinct addresses within block
#pragma unroll
  for (int dt4 = 0; dt4 < 16; ++dt4)
#pragma unroll
    for (int r = 0; r < 4; ++r) {
      const int m = w * 16 + r4 + r;
      const int d = dt4 * 16 + l15;
      atomicAdd(&tokens[((size_t)(b * M + m)) * D + d], acc2[dt4][r]);
    }
}

// ---------------------------------------------------------------------------
// K_FA: fused token stage, one block per (b,h), 256 threads.
// grid (B*H), block 256
__global__ __launch_bounds__(256) void k_fa(
    const float* __restrict__ tokens, const unsigned short* __restrict__ WqkvB,
    const unsigned short* __restrict__ WoB, const float* __restrict__ denom,
    float* __restrict__ tokO) {
  __shared__ __align__(16) char smem[84480];
  unsigned short* const At = reinterpret_cast<unsigned short*>(smem);          // [64][264]
  unsigned short* const Wq = reinterpret_cast<unsigned short*>(smem + 33792);  // [96][264]
  float* const qt = reinterpret_cast<float*>(smem);            // [32][68]
  float* const kt = reinterpret_cast<float*>(smem + 8704);     // [32][68]
  float* const vv = reinterpret_cast<float*>(smem + 17408);    // [64][36]
  float* const P  = reinterpret_cast<float*>(smem + 26624);    // [64][68]
  float* const ao = reinterpret_cast<float*>(smem + 44032);    // [64][36]
  const int b = blockIdx.x >> 3;
  const int h = blockIdx.x & 7;
  const int tid = threadIdx.x;
  const int w = tid >> 6, l = tid & 63;
  const int l15 = l & 15;
  const int q8 = (l >> 4) * 8;
  const int r4 = (l >> 4) * 4;

  // Phase 1: stage At + Wq
#pragma unroll
  for (int p = 0; p < 16; ++p) {
    const int i = p * 256 + tid;
    const int row = i >> 6;
    const int c4 = (i & 63) * 4;
    float4 av = ld4(&tokens[((size_t)(b * M + row)) * D + c4]);
    unsigned a0 = (unsigned)f2bf(av.x) | ((unsigned)f2bf(av.y) << 16);
    unsigned a1 = (unsigned)f2bf(av.z) | ((unsigned)f2bf(av.w) << 16);
    *reinterpret_cast<uint2*>(&At[row * 264 + c4]) = make_uint2(a0, a1);
  }
#pragma unroll
  for (int p = 0; p < 12; ++p) {
    const int u = p * 256 + tid;
    const int row = u >> 5;          // 0..95
    const int c = (u & 31) * 8;
    const int eg = (row < 32) ? (h * 32 + row)
                 : (row < 64) ? (256 + h * 32 + row - 32)
                              : (512 + h * 32 + row - 64);
    *reinterpret_cast<short8*>(&Wq[row * 264 + c]) =
        *reinterpret_cast<const short8*>(&WqkvB[(size_t)eg * 256 + c]);
  }
  float rcp4[4];
#pragma unroll
  for (int r = 0; r < 4; ++r)
    rcp4[r] = 1.0f / denom[b * M + w * 16 + r4 + r];
  __syncthreads();

  // Phase 2: GEMM1 (wave w -> rows w*16..w*16+15, 6 e-tiles)
  floatx4 acc[6] = {{0.f, 0.f, 0.f, 0.f}, {0.f, 0.f, 0.f, 0.f},
                    {0.f, 0.f, 0.f, 0.f}, {0.f, 0.f, 0.f, 0.f},
                    {0.f, 0.f, 0.f, 0.f}, {0.f, 0.f, 0.f, 0.f}};
  const int arow = w * 16 + l15;
#pragma unroll
  for (int ks = 0; ks < 8; ++ks) {
    short8 a = *reinterpret_cast<short8*>(&At[arow * 264 + ks * 32 + q8]);
#pragma unroll
    for (int et = 0; et < 6; ++et) {
      short8 bf = *reinterpret_cast<short8*>(&Wq[(et * 16 + l15) * 264 + ks * 32 + q8]);
      acc[et] = __builtin_amdgcn_mfma_f32_16x16x32_bf16(a, bf, acc[et], 0, 0, 0);
    }
  }
  // preload Wo B-frags for phase 5 (latency hidden under attention)
  short8 wof[4];
#pragma unroll
  for (int dt4 = 0; dt4 < 4; ++dt4)
    wof[dt4] = *reinterpret_cast<const short8*>(
        &WoB[(size_t)(w * 64 + dt4 * 16 + l15) * 256 + h * 32 + q8]);
  __syncthreads();  // all waves done reading At/Wq; overlay region free

  // Phase 3: qkv -> qt/kt/vv (normalized)
#pragma unroll
  for (int r = 0; r < 4; ++r) {
    const int m = w * 16 + r4 + r;
    const float rc = rcp4[r];
#pragma unroll
    for (int et = 0; et < 6; ++et) {
      const float val = acc[et][r] * rc;
      const int c = (et & 1) * 16 + l15;
      if (et < 2) qt[c * 68 + m] = val;
      else if (et < 4) kt[c * 68 + m] = val;
      else vv[m * 36 + c] = val;
    }
  }
  __syncthreads();

  // Phase 4a: S = q.k^T * scale
  {
    const int tm4 = (tid & 15) * 4;
    const int tn4 = (tid >> 4) * 4;
    float sacc[4][4] = {};
    for (int k = 0; k < 32; ++k) {
      float4 a4 = ld4(&qt[k * 68 + tn4]);
      float4 b4 = ld4(&kt[k * 68 + tm4]);
#pragma unroll
      for (int i = 0; i < 4; ++i) {
        const float av = (i == 0) ? a4.x : (i == 1) ? a4.y : (i == 2) ? a4.z : a4.w;
        sacc[i][0] = fmaf(av, b4.x, sacc[i][0]);
        sacc[i][1] = fmaf(av, b4.y, sacc[i][1]);
        sacc[i][2] = fmaf(av, b4.z, sacc[i][2]);
        sacc[i][3] = fmaf(av, b4.w, sacc[i][3]);
      }
    }
    const float scale = 0.17677669529663687f;
#pragma unroll
    for (int i = 0; i < 4; ++i)
      *reinterpret_cast<float4*>(&P[(tn4 + i) * 68 + tm4]) =
          make_float4(sacc[i][0] * scale, sacc[i][1] * scale,
                      sacc[i][2] * scale, sacc[i][3] * scale);
  }
  __syncthreads();
  // Phase 4b: softmax over rows
  if (tid < 64) {
    float mx = -1e30f;
    for (int j = 0; j < 64; ++j) mx = fmaxf(mx, P[tid * 68 + j]);
    float s = 0.0f;
    for (int j = 0; j < 64; ++j) {
      const float e = expf(P[tid * 68 + j] - mx);
      P[tid * 68 + j] = e;
      s += e;
    }
    const float r = 1.0f / s;
    for (int j = 0; j < 64; ++j) P[tid * 68 + j] *= r;
  }
  __syncthreads();
  // Phase 4c: PV -> ao[m][hd]
  if (tid < 128) {
    const int i0 = (tid >> 3) * 4;
    const int c0 = (tid & 7) * 4;
    float o[4][4] = {};
    for (int j = 0; j < 64; ++j) {
      float4 v4 = ld4(&vv[j * 36 + c0]);
#pragma unroll
      for (int ii = 0; ii < 4; ++ii) {
        const float p = P[(i0 + ii) * 68 + j];
        o[ii][0] = fmaf(p, v4.x, o[ii][0]);
        o[ii][1] = fmaf(p, v4.y, o[ii][1]);
        o[ii][2] = fmaf(p, v4.z, o[ii][2]);
        o[ii][3] = fmaf(p, v4.w, o[ii][3]);
      }
    }
#pragma unroll
    for (int ii = 0; ii < 4; ++ii)
#pragma unroll
      for (int jj = 0; jj < 4; ++jj) ao[(i0 + ii) * 36 + c0 + jj] = o[ii][jj];
  }
  __syncthreads();

  // Phase 5: partial out-proj, K=32 (this head's e-slice), wave w -> d-cols w*64..
  floatx4 acc2[4][4] = {{{0.f, 0.f, 0.f, 0.f}, {0.f, 0.f, 0.f, 0.f},
                         {0.f, 0.f, 0.f, 0.f}, {0.f, 0.f, 0.f, 0.f}},
                        {{0.f, 0.f, 0.f, 0.f}, {0.f, 0.f, 0.f, 0.f},
                         {0.f, 0.f, 0.f, 0.f}, {0.f, 0.f, 0.f, 0.f}},
                        {{0.f, 0.f, 0.f, 0.f}, {0.f, 0.f, 0.f, 0.f},
                         {0.f, 0.f, 0.f, 0.f}, {0.f, 0.f, 0.f, 0.f}},
                        {{0.f, 0.f, 0.f, 0.f}, {0.f, 0.f, 0.f, 0.f},
                         {0.f, 0.f, 0.f, 0.f}, {0.f, 0.f, 0.f, 0.f}}};
#pragma unroll
  for (int mt = 0; mt < 4; ++mt) {
    short8 af;
#pragma unroll
    for (int j = 0; j < 8; ++j)
      af[j] = (short)f2bf(ao[(mt * 16 + l15) * 36 + q8 + j]);
#pragma unroll
    for (int dt4 = 0; dt4 < 4; ++dt4)
      acc2[mt][dt4] =
          __builtin_amdgcn_mfma_f32_16x16x32_bf16(af, wof[dt4], acc2[mt][dt4], 0, 0, 0);
  }
#pragma unroll
  for (int mt = 0; mt < 4; ++mt)
#pragma unroll
    for (int dt4 = 0; dt4 < 4; ++dt4)
#pragma unroll
      for (int r = 0; r < 4; ++r) {
        const int m = mt * 16 + r4 + r;
        const int d = w * 64 + dt4 * 16 + l15;
        atomicAdd(&tokO[((size_t)(b * M + m)) * D + d], acc2[mt][dt4][r]);
      }
}

// ---------------------------------------------------------------------------
// K6: out[b,n,d] = sum_m En[b,n,m] * token_out[b,m,d]   (MFMA, K=64)
// Finalize inlined: token_out = (tokO + bo) * rcp(denom) per block into
// TpS[d-local][m]. 128-n tiles, 8 waves. grid (D/64, N/128, B), block 512
__global__ __launch_bounds__(512, 4) void k6_unpool(
    const unsigned short* __restrict__ En, const float* __restrict__ tokO,
    const float* __restrict__ denom, const float* __restrict__ bo,
    float* __restrict__ out) {
  __shared__ unsigned short EnS[128][72];
  __shared__ unsigned short TpS[64][72];
  const int dt = blockIdx.x, nt = blockIdx.y, b = blockIdx.z;
  const int n0 = nt * 128, d0 = dt * 64;
  const int tid = threadIdx.x;
  const int w = tid >> 6, l = tid & 63;
  const int l15 = l & 15;
  const int q8 = (l >> 4) * 8;
  // stage En rows n0..n0+127
#pragma unroll
  for (int p = 0; p < 2; ++p) {
    const int g = p * 512 + tid;
    const int row = g >> 3;
    const int c8 = (g & 7) * 8;
    *reinterpret_cast<short8*>(&EnS[row][c8]) =
        *reinterpret_cast<const short8*>(
            &En[((size_t)(b * N + n0 + row)) * M + c8]);
  }
  // finalize token_out chunk [64 m][64 d] -> TpS[d-local][m] bf16
  {
    const int m = tid >> 3;
    const int c8 = (tid & 7) * 8;
    const float rc = 1.0f / denom[b * M + m];
    const float* tp = &tokO[((size_t)(b * M + m)) * D + d0 + c8];
    float4 v0 = ld4(tp);
    float4 v1 = ld4(tp + 4);
    float4 bb0 = ld4(&bo[d0 + c8]);
    float4 bb1 = ld4(&bo[d0 + c8 + 4]);
    TpS[c8 + 0][m] = f2bf((v0.x + bb0.x) * rc);
    TpS[c8 + 1][m] = f2bf((v0.y + bb0.y) * rc);
    TpS[c8 + 2][m] = f2bf((v0.z + bb0.z) * rc);
    TpS[c8 + 3][m] = f2bf((v0.w + bb0.w) * rc);
    TpS[c8 + 4][m] = f2bf((v1.x + bb1.x) * rc);
    TpS[c8 + 5][m] = f2bf((v1.y + bb1.y) * rc);
    TpS[c8 + 6][m] = f2bf((v1.z + bb1.z) * rc);
    TpS[c8 + 7][m] = f2bf((v1.w + bb1.w) * rc);
  }
  __syncthreads();
  floatx4 acc[4] = {{0.f, 0.f, 0.f, 0.f},
                    {0.f, 0.f, 0.f, 0.f},
                    {0.f, 0.f, 0.f, 0.f},
                    {0.f, 0.f, 0.f, 0.f}};
  const int arow = w * 16 + l15;
#pragma unroll
  for (int ks = 0; ks < 2; ++ks) {
    short8 a = *reinterpret_cast<short8*>(&EnS[arow][ks * 32 + q8]);
#pragma unroll
    for (int dtile = 0; dtile < 4; ++dtile) {
      short8 bf = *reinterpret_cast<short8*>(
          &TpS[dtile * 16 + l15][ks * 32 + q8]);
      acc[dtile] =
          __builtin_amdgcn_mfma_f32_16x16x32_bf16(a, bf, acc[dtile], 0, 0, 0);
    }
  }
#pragma unroll
  for (int dtile = 0; dtile < 4; ++dtile)
#pragma unroll
    for (int r = 0; r < 4; ++r) {
      const int n = n0 + w * 16 + (l >> 4) * 4 + r;
      const int d = d0 + dtile * 16 + l15;
      out[((size_t)(b * N + n)) * D + d] = acc[dtile][r];
    }
}

// ---------------------------------------------------------------------------
extern "C" void kernel_launch(void* const* d_in, const int* in_sizes, int n_in,
                              void* d_out, int out_size, void* d_ws,
                              size_t ws_size, hipStream_t stream) {
  const float* x = (const float*)d_in[0];
  const float* Ws = (const float*)d_in[1];
  const float* bs = (const float*)d_in[2];
  const float* Wqkv = (const float*)d_in[3];
  const float* Wo = (const float*)d_in[4];
  const float* bo = (const float*)d_in[5];
  float* out = (float*)d_out;

  char* p = (char*)d_ws;
  unsigned short* En = (unsigned short*)p;    p += (size_t)B * N * M * 2;   // 8.4 MB
  float* denom = (float*)p;                   p += (size_t)B * M * 4;
  float* tokens = (float*)p;                  p += (size_t)B * M * D * 4;   // 256 KB
  float* tokO = (float*)p;                    p += (size_t)B * M * D * 4;   // 256 KB
  unsigned short* WsB = (unsigned short*)p;   p += (size_t)M * D * 2;       // 32 KB
  unsigned short* WqkvB = (unsigned short*)p; p += (size_t)3 * D * D * 2;   // 384 KB
  unsigned short* WoB = (unsigned short*)p;   p += (size_t)D * D * 2;       // 128 KB

  k0_prep<<<dim3(136), 256, 0, stream>>>(Ws, Wqkv, Wo, WsB, WqkvB, WoB,
                                         denom, tokens, tokO);
  k12_fused<<<dim3(N / 128, B), 256, 0, stream>>>(x, WsB, bs, En, denom,
                                                  tokens);
  k_fa<<<dim3(B * H), 256, 0, stream>>>(tokens, WqkvB, WoB, denom, tokO);
  k6_unpool<<<dim3(D / 64, N / 128, B), 512, 0, stream>>>(En, tokO, denom, bo,
                                                          out);
}

// Round 7
// 174.369 us; speedup vs baseline: 1.0113x; 1.0113x over previous
//
#include <hip/hip_runtime.h>
#include <math.h>

constexpr int B = 4;
constexpr int N = 16384;
constexpr int D = 256;
constexpr int M = 64;
constexpr int H = 8;
// HD = 32, 3D = 768

typedef __attribute__((ext_vector_type(8))) short short8;
typedef __attribute__((ext_vector_type(4))) float floatx4;

__device__ __forceinline__ float4 ld4(const float* p) {
  return *reinterpret_cast<const float4*>(p);
}
__device__ __forceinline__ unsigned short f2bf(float f) {
  unsigned u = __float_as_uint(f);
  unsigned r = (u + 0x7fffu + ((u >> 16) & 1u)) >> 16;  // RNE
  return (unsigned short)r;
}

// ---------------------------------------------------------------------------
// K0: one-time fp32 -> bf16 conversion of Ws (64x256), Wqkv (768x256),
// Wo (256x256); also zeroes denom, tokens, tokO. grid 136 x 256.
__global__ __launch_bounds__(256) void k0_prep(
    const float* __restrict__ Ws, const float* __restrict__ Wqkv,
    const float* __restrict__ Wo, unsigned short* __restrict__ WsB,
    unsigned short* __restrict__ WqkvB, unsigned short* __restrict__ WoB,
    float* __restrict__ denom, float* __restrict__ tokens,
    float* __restrict__ tokO) {
  const int g = blockIdx.x * 256 + threadIdx.x;
  if (g < 32768) {
    *reinterpret_cast<float2*>(&tokens[g * 2]) = make_float2(0.f, 0.f);
    *reinterpret_cast<float2*>(&tokO[g * 2]) = make_float2(0.f, 0.f);
  }
  if (g < 128)
    *reinterpret_cast<float2*>(&denom[g * 2]) = make_float2(0.f, 0.f);
  const float* src;
  unsigned short* dst;
  int off;
  if (g < 2048) {
    src = Ws; dst = WsB; off = g;
  } else if (g < 26624) {
    src = Wqkv; dst = WqkvB; off = g - 2048;
  } else {
    src = Wo; dst = WoB; off = g - 26624;
  }
  const float4 a = ld4(&src[(size_t)off * 8]);
  const float4 c = ld4(&src[(size_t)off * 8 + 4]);
  unsigned d0 = (unsigned)f2bf(a.x) | ((unsigned)f2bf(a.y) << 16);
  unsigned d1 = (unsigned)f2bf(a.z) | ((unsigned)f2bf(a.w) << 16);
  unsigned d2 = (unsigned)f2bf(c.x) | ((unsigned)f2bf(c.y) << 16);
  unsigned d3 = (unsigned)f2bf(c.z) | ((unsigned)f2bf(c.w) << 16);
  *reinterpret_cast<uint4*>(&dst[(size_t)off * 8]) = make_uint4(d0, d1, d2, d3);
}

// ---------------------------------------------------------------------------
// K12 (fused logits + exp + En + pooling), latency-overlapped:
//   - subtile-0 x loads issued BEFORE Wt staging
//   - subtile-1 x loads issued during subtile-0 compute (prefetch; VGPR ~190,
//     free since occupancy is LDS-bound at 2 blocks/CU)
//   - XsT scatter right after cvt -> ds_writes overlap logits MFMAs
//   - EsT scatter merged into exp loop; one barrier before pool, one after
//   - __expf (2-ulp; invisible under bf16 rounding of E)
// grid (N/128, B), block 256 (4 waves).
__global__ __launch_bounds__(256, 2) void k12_fused(
    const float* __restrict__ x, const unsigned short* __restrict__ WsB,
    const float* __restrict__ bs, unsigned short* __restrict__ En,
    float* __restrict__ denom, float* __restrict__ tokens) {
  __shared__ unsigned short Wt[64][264];   // Ws [m][d] bf16 (33792 B)
  __shared__ unsigned short EsT[64][70];   // E^T [m][n-local] (8960 B)
  __shared__ unsigned short XsT[256][70];  // x^T [d][n-local] (35840 B)
  __shared__ float red[64];
  const int b = blockIdx.y;
  const int nb0 = blockIdx.x * 128;
  const int tid = threadIdx.x;
  const int w = tid >> 6, l = tid & 63;
  const int l15 = l & 15;
  const int q8 = (l >> 4) * 8;
  const int r4 = (l >> 4) * 4;
  const int ar = w * 16 + l15;  // this thread's n-row within 64-subtile

  // issue subtile-0 x loads first (in flight during Wt staging)
  float4 fx0[16];
  {
    const float* xr = &x[((size_t)(b * N + nb0 + ar)) * D];
#pragma unroll
    for (int ks = 0; ks < 8; ++ks) {
      fx0[2 * ks] = ld4(&xr[ks * 32 + q8]);
      fx0[2 * ks + 1] = ld4(&xr[ks * 32 + q8 + 4]);
    }
  }
  // stage Ws once
#pragma unroll
  for (int p = 0; p < 8; ++p) {
    const int u = p * 256 + tid;
    const int row = u >> 5;
    const int c = (u & 31) * 8;
    *reinterpret_cast<short8*>(&Wt[row][c]) =
        *reinterpret_cast<const short8*>(&WsB[(size_t)row * 256 + c]);
  }
  if (tid < 64) red[tid] = 0.0f;
  __syncthreads();

  floatx4 acc2[16];
#pragma unroll
  for (int i = 0; i < 16; ++i) acc2[i] = {0.f, 0.f, 0.f, 0.f};

  float4 fx1[16];
  short8 afr[8];
  floatx4 acc[4];

#define K12_CVT(FX)                                                    \
  do {                                                                 \
    _Pragma("unroll") for (int ks = 0; ks < 8; ++ks) {                 \
      const float4 a0 = FX[2 * ks], a1 = FX[2 * ks + 1];               \
      short8 tt;                                                       \
      tt[0] = (short)f2bf(a0.x); tt[1] = (short)f2bf(a0.y);            \
      tt[2] = (short)f2bf(a0.z); tt[3] = (short)f2bf(a0.w);            \
      tt[4] = (short)f2bf(a1.x); tt[5] = (short)f2bf(a1.y);            \
      tt[6] = (short)f2bf(a1.z); tt[7] = (short)f2bf(a1.w);            \
      afr[ks] = tt;                                                    \
    }                                                                  \
  } while (0)

#define K12_SCATTER()                                                  \
  do {                                                                 \
    _Pragma("unroll") for (int ks = 0; ks < 8; ++ks)                   \
        _Pragma("unroll") for (int j = 0; j < 8; ++j)                  \
            XsT[ks * 32 + q8 + j][ar] = (unsigned short)afr[ks][j];    \
  } while (0)

#define K12_LOGITS()                                                   \
  do {                                                                 \
    _Pragma("unroll") for (int i = 0; i < 4; ++i)                      \
        acc[i] = {0.f, 0.f, 0.f, 0.f};                                 \
    _Pragma("unroll") for (int ks = 0; ks < 8; ++ks) {                 \
      _Pragma("unroll") for (int mt = 0; mt < 4; ++mt) {               \
        short8 bf =                                                    \
            *reinterpret_cast<short8*>(&Wt[mt * 16 + l15][ks * 32 + q8]); \
        acc[mt] = __builtin_amdgcn_mfma_f32_16x16x32_bf16(afr[ks], bf, \
                                                          acc[mt], 0, 0, 0); \
      }                                                                \
    }                                                                  \
  } while (0)

#define K12_EPILOG(N0)                                                 \
  do {                                                                 \
    _Pragma("unroll") for (int mt = 0; mt < 4; ++mt) {                 \
      const int m = mt * 16 + l15;                                     \
      const float bsm = bs[m];                                         \
      float s = 0.0f;                                                  \
      _Pragma("unroll") for (int r = 0; r < 4; ++r) {                  \
        const int n = w * 16 + r4 + r;                                 \
        const float e = __expf(acc[mt][r] + bsm);                      \
        s += e;                                                        \
        const unsigned short eb = f2bf(e);                             \
        EsT[m][w * 16 + r4 + r] = eb;                                  \
        En[((size_t)(b * N + (N0) + n)) * M + m] = eb;                 \
      }                                                                \
      atomicAdd(&red[m], s);                                           \
    }                                                                  \
  } while (0)

#define K12_POOL()                                                     \
  do {                                                                 \
    _Pragma("unroll") for (int ks2 = 0; ks2 < 2; ++ks2) {              \
      const int nf = ks2 * 32 + q8;                                    \
      short8 a = *reinterpret_cast<short8*>(&EsT[w * 16 + l15][nf]);   \
      _Pragma("unroll") for (int dt4 = 0; dt4 < 16; ++dt4) {           \
        short8 bf = *reinterpret_cast<short8*>(&XsT[dt4 * 16 + l15][nf]); \
        acc2[dt4] = __builtin_amdgcn_mfma_f32_16x16x32_bf16(a, bf,     \
                                                            acc2[dt4], 0, 0, 0); \
      }                                                                \
    }                                                                  \
  } while (0)

  // ---- subtile 0 ----
  K12_CVT(fx0);
  {  // prefetch subtile 1 (hidden under subtile-0 compute)
    const float* xr = &x[((size_t)(b * N + nb0 + 64 + ar)) * D];
#pragma unroll
    for (int ks = 0; ks < 8; ++ks) {
      fx1[2 * ks] = ld4(&xr[ks * 32 + q8]);
      fx1[2 * ks + 1] = ld4(&xr[ks * 32 + q8 + 4]);
    }
  }
  K12_SCATTER();   // ds_writes overlap the MFMAs below
  K12_LOGITS();
  K12_EPILOG(nb0);
  __syncthreads();  // XsT/EsT staged by all waves
  K12_POOL();
  __syncthreads();  // pool reads done; safe to overwrite XsT/EsT

  // ---- subtile 1 ----
  K12_CVT(fx1);
  K12_SCATTER();
  K12_LOGITS();
  K12_EPILOG(nb0 + 64);
  __syncthreads();
  K12_POOL();

  // ---- flush ----
  if (tid < 64) atomicAdd(&denom[b * M + tid], red[tid]);
#pragma unroll
  for (int dt4 = 0; dt4 < 16; ++dt4)
#pragma unroll
    for (int r = 0; r < 4; ++r) {
      const int m = w * 16 + r4 + r;
      const int d = dt4 * 16 + l15;
      atomicAdd(&tokens[((size_t)(b * M + m)) * D + d], acc2[dt4][r]);
    }
#undef K12_CVT
#undef K12_SCATTER
#undef K12_LOGITS
#undef K12_EPILOG
#undef K12_POOL
}

// ---------------------------------------------------------------------------
// K_FA: fused token stage, one block per (b,h), 256 threads.
// grid (B*H), block 256
__global__ __launch_bounds__(256) void k_fa(
    const float* __restrict__ tokens, const unsigned short* __restrict__ WqkvB,
    const unsigned short* __restrict__ WoB, const float* __restrict__ denom,
    float* __restrict__ tokO) {
  __shared__ __align__(16) char smem[84480];
  unsigned short* const At = reinterpret_cast<unsigned short*>(smem);          // [64][264]
  unsigned short* const Wq = reinterpret_cast<unsigned short*>(smem + 33792);  // [96][264]
  float* const qt = reinterpret_cast<float*>(smem);            // [32][68]
  float* const kt = reinterpret_cast<float*>(smem + 8704);     // [32][68]
  float* const vv = reinterpret_cast<float*>(smem + 17408);    // [64][36]
  float* const P  = reinterpret_cast<float*>(smem + 26624);    // [64][68]
  float* const ao = reinterpret_cast<float*>(smem + 44032);    // [64][36]
  const int b = blockIdx.x >> 3;
  const int h = blockIdx.x & 7;
  const int tid = threadIdx.x;
  const int w = tid >> 6, l = tid & 63;
  const int l15 = l & 15;
  const int q8 = (l >> 4) * 8;
  const int r4 = (l >> 4) * 4;

  // Phase 1: stage At + Wq
#pragma unroll
  for (int p = 0; p < 16; ++p) {
    const int i = p * 256 + tid;
    const int row = i >> 6;
    const int c4 = (i & 63) * 4;
    float4 av = ld4(&tokens[((size_t)(b * M + row)) * D + c4]);
    unsigned a0 = (unsigned)f2bf(av.x) | ((unsigned)f2bf(av.y) << 16);
    unsigned a1 = (unsigned)f2bf(av.z) | ((unsigned)f2bf(av.w) << 16);
    *reinterpret_cast<uint2*>(&At[row * 264 + c4]) = make_uint2(a0, a1);
  }
#pragma unroll
  for (int p = 0; p < 12; ++p) {
    const int u = p * 256 + tid;
    const int row = u >> 5;          // 0..95
    const int c = (u & 31) * 8;
    const int eg = (row < 32) ? (h * 32 + row)
                 : (row < 64) ? (256 + h * 32 + row - 32)
                              : (512 + h * 32 + row - 64);
    *reinterpret_cast<short8*>(&Wq[row * 264 + c]) =
        *reinterpret_cast<const short8*>(&WqkvB[(size_t)eg * 256 + c]);
  }
  float rcp4[4];
#pragma unroll
  for (int r = 0; r < 4; ++r)
    rcp4[r] = 1.0f / denom[b * M + w * 16 + r4 + r];
  __syncthreads();

  // Phase 2: GEMM1 (wave w -> rows w*16..w*16+15, 6 e-tiles)
  floatx4 acc[6] = {{0.f, 0.f, 0.f, 0.f}, {0.f, 0.f, 0.f, 0.f},
                    {0.f, 0.f, 0.f, 0.f}, {0.f, 0.f, 0.f, 0.f},
                    {0.f, 0.f, 0.f, 0.f}, {0.f, 0.f, 0.f, 0.f}};
  const int arow = w * 16 + l15;
#pragma unroll
  for (int ks = 0; ks < 8; ++ks) {
    short8 a = *reinterpret_cast<short8*>(&At[arow * 264 + ks * 32 + q8]);
#pragma unroll
    for (int et = 0; et < 6; ++et) {
      short8 bf = *reinterpret_cast<short8*>(&Wq[(et * 16 + l15) * 264 + ks * 32 + q8]);
      acc[et] = __builtin_amdgcn_mfma_f32_16x16x32_bf16(a, bf, acc[et], 0, 0, 0);
    }
  }
  // preload Wo B-frags for phase 5 (latency hidden under attention)
  short8 wof[4];
#pragma unroll
  for (int dt4 = 0; dt4 < 4; ++dt4)
    wof[dt4] = *reinterpret_cast<const short8*>(
        &WoB[(size_t)(w * 64 + dt4 * 16 + l15) * 256 + h * 32 + q8]);
  __syncthreads();  // all waves done reading At/Wq; overlay region free

  // Phase 3: qkv -> qt/kt/vv (normalized)
#pragma unroll
  for (int r = 0; r < 4; ++r) {
    const int m = w * 16 + r4 + r;
    const float rc = rcp4[r];
#pragma unroll
    for (int et = 0; et < 6; ++et) {
      const float val = acc[et][r] * rc;
      const int c = (et & 1) * 16 + l15;
      if (et < 2) qt[c * 68 + m] = val;
      else if (et < 4) kt[c * 68 + m] = val;
      else vv[m * 36 + c] = val;
    }
  }
  __syncthreads();

  // Phase 4a: S = q.k^T * scale
  {
    const int tm4 = (tid & 15) * 4;
    const int tn4 = (tid >> 4) * 4;
    float sacc[4][4] = {};
    for (int k = 0; k < 32; ++k) {
      float4 a4 = ld4(&qt[k * 68 + tn4]);
      float4 b4 = ld4(&kt[k * 68 + tm4]);
#pragma unroll
      for (int i = 0; i < 4; ++i) {
        const float av = (i == 0) ? a4.x : (i == 1) ? a4.y : (i == 2) ? a4.z : a4.w;
        sacc[i][0] = fmaf(av, b4.x, sacc[i][0]);
        sacc[i][1] = fmaf(av, b4.y, sacc[i][1]);
        sacc[i][2] = fmaf(av, b4.z, sacc[i][2]);
        sacc[i][3] = fmaf(av, b4.w, sacc[i][3]);
      }
    }
    const float scale = 0.17677669529663687f;
#pragma unroll
    for (int i = 0; i < 4; ++i)
      *reinterpret_cast<float4*>(&P[(tn4 + i) * 68 + tm4]) =
          make_float4(sacc[i][0] * scale, sacc[i][1] * scale,
                      sacc[i][2] * scale, sacc[i][3] * scale);
  }
  __syncthreads();
  // Phase 4b: softmax over rows
  if (tid < 64) {
    float mx = -1e30f;
    for (int j = 0; j < 64; ++j) mx = fmaxf(mx, P[tid * 68 + j]);
    float s = 0.0f;
    for (int j = 0; j < 64; ++j) {
      const float e = expf(P[tid * 68 + j] - mx);
      P[tid * 68 + j] = e;
      s += e;
    }
    const float r = 1.0f / s;
    for (int j = 0; j < 64; ++j) P[tid * 68 + j] *= r;
  }
  __syncthreads();
  // Phase 4c: PV -> ao[m][hd]
  if (tid < 128) {
    const int i0 = (tid >> 3) * 4;
    const int c0 = (tid & 7) * 4;
    float o[4][4] = {};
    for (int j = 0; j < 64; ++j) {
      float4 v4 = ld4(&vv[j * 36 + c0]);
#pragma unroll
      for (int ii = 0; ii < 4; ++ii) {
        const float p = P[(i0 + ii) * 68 + j];
        o[ii][0] = fmaf(p, v4.x, o[ii][0]);
        o[ii][1] = fmaf(p, v4.y, o[ii][1]);
        o[ii][2] = fmaf(p, v4.z, o[ii][2]);
        o[ii][3] = fmaf(p, v4.w, o[ii][3]);
      }
    }
#pragma unroll
    for (int ii = 0; ii < 4; ++ii)
#pragma unroll
      for (int jj = 0; jj < 4; ++jj) ao[(i0 + ii) * 36 + c0 + jj] = o[ii][jj];
  }
  __syncthreads();

  // Phase 5: partial out-proj, K=32 (this head's e-slice), wave w -> d-cols w*64..
  floatx4 acc2[4][4] = {{{0.f, 0.f, 0.f, 0.f}, {0.f, 0.f, 0.f, 0.f},
                         {0.f, 0.f, 0.f, 0.f}, {0.f, 0.f, 0.f, 0.f}},
                        {{0.f, 0.f, 0.f, 0.f}, {0.f, 0.f, 0.f, 0.f},
                         {0.f, 0.f, 0.f, 0.f}, {0.f, 0.f, 0.f, 0.f}},
                        {{0.f, 0.f, 0.f, 0.f}, {0.f, 0.f, 0.f, 0.f},
                         {0.f, 0.f, 0.f, 0.f}, {0.f, 0.f, 0.f, 0.f}},
                        {{0.f, 0.f, 0.f, 0.f}, {0.f, 0.f, 0.f, 0.f},
                         {0.f, 0.f, 0.f, 0.f}, {0.f, 0.f, 0.f, 0.f}}};
#pragma unroll
  for (int mt = 0; mt < 4; ++mt) {
    short8 af;
#pragma unroll
    for (int j = 0; j < 8; ++j)
      af[j] = (short)f2bf(ao[(mt * 16 + l15) * 36 + q8 + j]);
#pragma unroll
    for (int dt4 = 0; dt4 < 4; ++dt4)
      acc2[mt][dt4] =
          __builtin_amdgcn_mfma_f32_16x16x32_bf16(af, wof[dt4], acc2[mt][dt4], 0, 0, 0);
  }
#pragma unroll
  for (int mt = 0; mt < 4; ++mt)
#pragma unroll
    for (int dt4 = 0; dt4 < 4; ++dt4)
#pragma unroll
      for (int r = 0; r < 4; ++r) {
        const int m = mt * 16 + r4 + r;
        const int d = w * 64 + dt4 * 16 + l15;
        atomicAdd(&tokO[((size_t)(b * M + m)) * D + d], acc2[mt][dt4][r]);
      }
}

// ---------------------------------------------------------------------------
// K6: out[b,n,d] = sum_m En[b,n,m] * token_out[b,m,d]   (MFMA, K=64)
// Finalize inlined: token_out = (tokO + bo) * rcp(denom) per block into
// TpS[d-local][m]. 128-n tiles, 8 waves. grid (D/64, N/128, B), block 512
__global__ __launch_bounds__(512, 4) void k6_unpool(
    const unsigned short* __restrict__ En, const float* __restrict__ tokO,
    const float* __restrict__ denom, const float* __restrict__ bo,
    float* __restrict__ out) {
  __shared__ unsigned short EnS[128][72];
  __shared__ unsigned short TpS[64][72];
  const int dt = blockIdx.x, nt = blockIdx.y, b = blockIdx.z;
  const int n0 = nt * 128, d0 = dt * 64;
  const int tid = threadIdx.x;
  const int w = tid >> 6, l = tid & 63;
  const int l15 = l & 15;
  const int q8 = (l >> 4) * 8;
  // stage En rows n0..n0+127
#pragma unroll
  for (int p = 0; p < 2; ++p) {
    const int g = p * 512 + tid;
    const int row = g >> 3;
    const int c8 = (g & 7) * 8;
    *reinterpret_cast<short8*>(&EnS[row][c8]) =
        *reinterpret_cast<const short8*>(
            &En[((size_t)(b * N + n0 + row)) * M + c8]);
  }
  // finalize token_out chunk [64 m][64 d] -> TpS[d-local][m] bf16
  {
    const int m = tid >> 3;
    const int c8 = (tid & 7) * 8;
    const float rc = 1.0f / denom[b * M + m];
    const float* tp = &tokO[((size_t)(b * M + m)) * D + d0 + c8];
    float4 v0 = ld4(tp);
    float4 v1 = ld4(tp + 4);
    float4 bb0 = ld4(&bo[d0 + c8]);
    float4 bb1 = ld4(&bo[d0 + c8 + 4]);
    TpS[c8 + 0][m] = f2bf((v0.x + bb0.x) * rc);
    TpS[c8 + 1][m] = f2bf((v0.y + bb0.y) * rc);
    TpS[c8 + 2][m] = f2bf((v0.z + bb0.z) * rc);
    TpS[c8 + 3][m] = f2bf((v0.w + bb0.w) * rc);
    TpS[c8 + 4][m] = f2bf((v1.x + bb1.x) * rc);
    TpS[c8 + 5][m] = f2bf((v1.y + bb1.y) * rc);
    TpS[c8 + 6][m] = f2bf((v1.z + bb1.z) * rc);
    TpS[c8 + 7][m] = f2bf((v1.w + bb1.w) * rc);
  }
  __syncthreads();
  floatx4 acc[4] = {{0.f, 0.f, 0.f, 0.f},
                    {0.f, 0.f, 0.f, 0.f},
                    {0.f, 0.f, 0.f, 0.f},
                    {0.f, 0.f, 0.f, 0.f}};
  const int arow = w * 16 + l15;
#pragma unroll
  for (int ks = 0; ks < 2; ++ks) {
    short8 a = *reinterpret_cast<short8*>(&EnS[arow][ks * 32 + q8]);
#pragma unroll
    for (int dtile = 0; dtile < 4; ++dtile) {
      short8 bf = *reinterpret_cast<short8*>(
          &TpS[dtile * 16 + l15][ks * 32 + q8]);
      acc[dtile] =
          __builtin_amdgcn_mfma_f32_16x16x32_bf16(a, bf, acc[dtile], 0, 0, 0);
    }
  }
#pragma unroll
  for (int dtile = 0; dtile < 4; ++dtile)
#pragma unroll
    for (int r = 0; r < 4; ++r) {
      const int n = n0 + w * 16 + (l >> 4) * 4 + r;
      const int d = d0 + dtile * 16 + l15;
      out[((size_t)(b * N + n)) * D + d] = acc[dtile][r];
    }
}

// ---------------------------------------------------------------------------
extern "C" void kernel_launch(void* const* d_in, const int* in_sizes, int n_in,
                              void* d_out, int out_size, void* d_ws,
                              size_t ws_size, hipStream_t stream) {
  const float* x = (const float*)d_in[0];
  const float* Ws = (const float*)d_in[1];
  const float* bs = (const float*)d_in[2];
  const float* Wqkv = (const float*)d_in[3];
  const float* Wo = (const float*)d_in[4];
  const float* bo = (const float*)d_in[5];
  float* out = (float*)d_out;

  char* p = (char*)d_ws;
  unsigned short* En = (unsigned short*)p;    p += (size_t)B * N * M * 2;   // 8.4 MB
  float* denom = (float*)p;                   p += (size_t)B * M * 4;
  float* tokens = (float*)p;                  p += (size_t)B * M * D * 4;   // 256 KB
  float* tokO = (float*)p;                    p += (size_t)B * M * D * 4;   // 256 KB
  unsigned short* WsB = (unsigned short*)p;   p += (size_t)M * D * 2;       // 32 KB
  unsigned short* WqkvB = (unsigned short*)p; p += (size_t)3 * D * D * 2;   // 384 KB
  unsigned short* WoB = (unsigned short*)p;   p += (size_t)D * D * 2;       // 128 KB

  k0_prep<<<dim3(136), 256, 0, stream>>>(Ws, Wqkv, Wo, WsB, WqkvB, WoB,
                                         denom, tokens, tokO);
  k12_fused<<<dim3(N / 128, B), 256, 0, stream>>>(x, WsB, bs, En, denom,
                                                  tokens);
  k_fa<<<dim3(B * H), 256, 0, stream>>>(tokens, WqkvB, WoB, denom, tokO);
  k6_unpool<<<dim3(D / 64, N / 128, B), 512, 0, stream>>>(En, tokO, denom, bo,
                                                          out);
}

// Round 8
// 168.597 us; speedup vs baseline: 1.0459x; 1.0342x over previous
//
#include <hip/hip_runtime.h>
#include <math.h>

constexpr int B = 4;
constexpr int N = 16384;
constexpr int D = 256;
constexpr int M = 64;
constexpr int H = 8;
// HD = 32, 3D = 768
constexpr int NSLOT = 128;  // k12 blocks per batch (N/128)

typedef __attribute__((ext_vector_type(8))) short short8;
typedef __attribute__((ext_vector_type(4))) float floatx4;

__device__ __forceinline__ float4 ld4(const float* p) {
  return *reinterpret_cast<const float4*>(p);
}
__device__ __forceinline__ unsigned short f2bf(float f) {
  unsigned u = __float_as_uint(f);
  unsigned r = (u + 0x7fffu + ((u >> 16) & 1u)) >> 16;  // RNE
  return (unsigned short)r;
}

// ---------------------------------------------------------------------------
// K0: one-time fp32 -> bf16 conversion of Ws (64x256), Wqkv (768x256),
// Wo (256x256); also zeroes denom and tokO. grid 136 x 256.
__global__ __launch_bounds__(256) void k0_prep(
    const float* __restrict__ Ws, const float* __restrict__ Wqkv,
    const float* __restrict__ Wo, unsigned short* __restrict__ WsB,
    unsigned short* __restrict__ WqkvB, unsigned short* __restrict__ WoB,
    float* __restrict__ denom, float* __restrict__ tokO) {
  const int g = blockIdx.x * 256 + threadIdx.x;
  if (g < 32768)
    *reinterpret_cast<float2*>(&tokO[g * 2]) = make_float2(0.f, 0.f);
  if (g < 128)
    *reinterpret_cast<float2*>(&denom[g * 2]) = make_float2(0.f, 0.f);
  const float* src;
  unsigned short* dst;
  int off;
  if (g < 2048) {
    src = Ws; dst = WsB; off = g;
  } else if (g < 26624) {
    src = Wqkv; dst = WqkvB; off = g - 2048;
  } else {
    src = Wo; dst = WoB; off = g - 26624;
  }
  const float4 a = ld4(&src[(size_t)off * 8]);
  const float4 c = ld4(&src[(size_t)off * 8 + 4]);
  unsigned d0 = (unsigned)f2bf(a.x) | ((unsigned)f2bf(a.y) << 16);
  unsigned d1 = (unsigned)f2bf(a.z) | ((unsigned)f2bf(a.w) << 16);
  unsigned d2 = (unsigned)f2bf(c.x) | ((unsigned)f2bf(c.y) << 16);
  unsigned d3 = (unsigned)f2bf(c.z) | ((unsigned)f2bf(c.w) << 16);
  *reinterpret_cast<uint4*>(&dst[(size_t)off * 8]) = make_uint4(d0, d1, d2, d3);
}

// ---------------------------------------------------------------------------
// K12 (fused logits + exp + En + pooling). Pool partials go to a PRIVATE
// per-block slot in tokensP via plain coalesced stores (no global atomics —
// the 8.4M-atomic/64K-address RMW storm was ~33MB of WRITE_SIZE and the k12
// tail bottleneck). k2r reduces the 128 slots afterwards.
// grid (N/128, B), block 256 (4 waves).
__global__ __launch_bounds__(256, 2) void k12_fused(
    const float* __restrict__ x, const unsigned short* __restrict__ WsB,
    const float* __restrict__ bs, unsigned short* __restrict__ En,
    float* __restrict__ denom, float* __restrict__ tokensP) {
  __shared__ unsigned short Wt[64][264];   // Ws [m][d] bf16 (33792 B)
  __shared__ unsigned short EsT[64][70];   // E^T [m][n-local] (8960 B)
  __shared__ unsigned short XsT[256][70];  // x^T [d][n-local] (35840 B)
  __shared__ float red[64];
  const int b = blockIdx.y;
  const int nb0 = blockIdx.x * 128;
  const int tid = threadIdx.x;
  const int w = tid >> 6, l = tid & 63;
  const int l15 = l & 15;
  const int q8 = (l >> 4) * 8;
  const int r4 = (l >> 4) * 4;
  const int ar = w * 16 + l15;  // this thread's n-row within 64-subtile

  // issue subtile-0 x loads first (in flight during Wt staging)
  float4 fx0[16];
  {
    const float* xr = &x[((size_t)(b * N + nb0 + ar)) * D];
#pragma unroll
    for (int ks = 0; ks < 8; ++ks) {
      fx0[2 * ks] = ld4(&xr[ks * 32 + q8]);
      fx0[2 * ks + 1] = ld4(&xr[ks * 32 + q8 + 4]);
    }
  }
  // stage Ws once
#pragma unroll
  for (int p = 0; p < 8; ++p) {
    const int u = p * 256 + tid;
    const int row = u >> 5;
    const int c = (u & 31) * 8;
    *reinterpret_cast<short8*>(&Wt[row][c]) =
        *reinterpret_cast<const short8*>(&WsB[(size_t)row * 256 + c]);
  }
  if (tid < 64) red[tid] = 0.0f;
  __syncthreads();

  floatx4 acc2[16];
#pragma unroll
  for (int i = 0; i < 16; ++i) acc2[i] = {0.f, 0.f, 0.f, 0.f};

  float4 fx1[16];
  short8 afr0[8], afr1[8];
  floatx4 acc[4];

#define K12_CVT(FX, AFR)                                               \
  do {                                                                 \
    _Pragma("unroll") for (int ks = 0; ks < 8; ++ks) {                 \
      const float4 a0 = FX[2 * ks], a1 = FX[2 * ks + 1];               \
      short8 tt;                                                       \
      tt[0] = (short)f2bf(a0.x); tt[1] = (short)f2bf(a0.y);            \
      tt[2] = (short)f2bf(a0.z); tt[3] = (short)f2bf(a0.w);            \
      tt[4] = (short)f2bf(a1.x); tt[5] = (short)f2bf(a1.y);            \
      tt[6] = (short)f2bf(a1.z); tt[7] = (short)f2bf(a1.w);            \
      AFR[ks] = tt;                                                    \
    }                                                                  \
  } while (0)

#define K12_SCATTER(AFR)                                               \
  do {                                                                 \
    _Pragma("unroll") for (int ks = 0; ks < 8; ++ks)                   \
        _Pragma("unroll") for (int j = 0; j < 8; ++j)                  \
            XsT[ks * 32 + q8 + j][ar] = (unsigned short)AFR[ks][j];    \
  } while (0)

#define K12_LOGITS(AFR)                                                \
  do {                                                                 \
    _Pragma("unroll") for (int i = 0; i < 4; ++i)                      \
        acc[i] = {0.f, 0.f, 0.f, 0.f};                                 \
    _Pragma("unroll") for (int ks = 0; ks < 8; ++ks) {                 \
      _Pragma("unroll") for (int mt = 0; mt < 4; ++mt) {               \
        short8 bf =                                                    \
            *reinterpret_cast<short8*>(&Wt[mt * 16 + l15][ks * 32 + q8]); \
        acc[mt] = __builtin_amdgcn_mfma_f32_16x16x32_bf16(AFR[ks], bf, \
                                                          acc[mt], 0, 0, 0); \
      }                                                                \
    }                                                                  \
  } while (0)

#define K12_EPILOG(N0)                                                 \
  do {                                                                 \
    _Pragma("unroll") for (int mt = 0; mt < 4; ++mt) {                 \
      const int m = mt * 16 + l15;                                     \
      const float bsm = bs[m];                                         \
      float s = 0.0f;                                                  \
      _Pragma("unroll") for (int r = 0; r < 4; ++r) {                  \
        const int n = w * 16 + r4 + r;                                 \
        const float e = __expf(acc[mt][r] + bsm);                      \
        s += e;                                                        \
        const unsigned short eb = f2bf(e);                             \
        EsT[m][w * 16 + r4 + r] = eb;                                  \
        En[((size_t)(b * N + (N0) + n)) * M + m] = eb;                 \
      }                                                                \
      atomicAdd(&red[m], s);                                           \
    }                                                                  \
  } while (0)

#define K12_POOL()                                                     \
  do {                                                                 \
    _Pragma("unroll") for (int ks2 = 0; ks2 < 2; ++ks2) {              \
      const int nf = ks2 * 32 + q8;                                    \
      short8 a = *reinterpret_cast<short8*>(&EsT[w * 16 + l15][nf]);   \
      _Pragma("unroll") for (int dt4 = 0; dt4 < 16; ++dt4) {           \
        short8 bf = *reinterpret_cast<short8*>(&XsT[dt4 * 16 + l15][nf]); \
        acc2[dt4] = __builtin_amdgcn_mfma_f32_16x16x32_bf16(a, bf,     \
                                                            acc2[dt4], 0, 0, 0); \
      }                                                                \
    }                                                                  \
  } while (0)

  // ---- subtile 0 ----
  K12_CVT(fx0, afr0);
  {  // prefetch subtile 1 (hidden under subtile-0 compute)
    const float* xr = &x[((size_t)(b * N + nb0 + 64 + ar)) * D];
#pragma unroll
    for (int ks = 0; ks < 8; ++ks) {
      fx1[2 * ks] = ld4(&xr[ks * 32 + q8]);
      fx1[2 * ks + 1] = ld4(&xr[ks * 32 + q8 + 4]);
    }
  }
  K12_SCATTER(afr0);   // ds_writes overlap the MFMAs below
  K12_LOGITS(afr0);
  K12_EPILOG(nb0);
  K12_CVT(fx1, afr1);  // register-only; hoisted above the barrier
  __syncthreads();     // XsT/EsT staged by all waves
  K12_POOL();
  __syncthreads();     // pool reads done; safe to overwrite XsT/EsT

  // ---- subtile 1 ----
  K12_SCATTER(afr1);
  K12_LOGITS(afr1);
  K12_EPILOG(nb0 + 64);
  __syncthreads();
  K12_POOL();

  // ---- flush: plain stores into this block's private slot ----
  if (tid < 64) atomicAdd(&denom[b * M + tid], red[tid]);
  float* op = tokensP + ((size_t)(b * NSLOT + blockIdx.x) * M) * D;
#pragma unroll
  for (int dt4 = 0; dt4 < 16; ++dt4)
#pragma unroll
    for (int r = 0; r < 4; ++r)
      op[(w * 16 + r4 + r) * D + dt4 * 16 + l15] = acc2[dt4][r];
#undef K12_CVT
#undef K12_SCATTER
#undef K12_LOGITS
#undef K12_EPILOG
#undef K12_POOL
}

// ---------------------------------------------------------------------------
// K2R: tokens[b][m][d] = sum_{s<128} tokensP[b][s][m][d].
// grid (B*M) = 256 blocks, block 256 (thread = one d). Coalesced 1KB reads.
__global__ __launch_bounds__(256) void k2r_reduce(
    const float* __restrict__ tokensP, float* __restrict__ tokens) {
  const int b = blockIdx.x >> 6;
  const int m = blockIdx.x & 63;
  const int d = threadIdx.x;
  const float* base = tokensP + ((size_t)(b * NSLOT) * M + m) * D + d;
  float s0 = 0.f, s1 = 0.f, s2 = 0.f, s3 = 0.f;
#pragma unroll 4
  for (int s = 0; s < NSLOT; s += 4) {
    s0 += base[(size_t)(s + 0) * M * D];
    s1 += base[(size_t)(s + 1) * M * D];
    s2 += base[(size_t)(s + 2) * M * D];
    s3 += base[(size_t)(s + 3) * M * D];
  }
  tokens[((size_t)(b * M) + m) * D + d] = (s0 + s1) + (s2 + s3);
}

// ---------------------------------------------------------------------------
// K_FA: fused token stage, one block per (b,h), 256 threads.
// grid (B*H), block 256
__global__ __launch_bounds__(256) void k_fa(
    const float* __restrict__ tokens, const unsigned short* __restrict__ WqkvB,
    const unsigned short* __restrict__ WoB, const float* __restrict__ denom,
    float* __restrict__ tokO) {
  __shared__ __align__(16) char smem[84480];
  unsigned short* const At = reinterpret_cast<unsigned short*>(smem);          // [64][264]
  unsigned short* const Wq = reinterpret_cast<unsigned short*>(smem + 33792);  // [96][264]
  float* const qt = reinterpret_cast<float*>(smem);            // [32][68]
  float* const kt = reinterpret_cast<float*>(smem + 8704);     // [32][68]
  float* const vv = reinterpret_cast<float*>(smem + 17408);    // [64][36]
  float* const P  = reinterpret_cast<float*>(smem + 26624);    // [64][68]
  float* const ao = reinterpret_cast<float*>(smem + 44032);    // [64][36]
  const int b = blockIdx.x >> 3;
  const int h = blockIdx.x & 7;
  const int tid = threadIdx.x;
  const int w = tid >> 6, l = tid & 63;
  const int l15 = l & 15;
  const int q8 = (l >> 4) * 8;
  const int r4 = (l >> 4) * 4;

  // Phase 1: stage At + Wq
#pragma unroll
  for (int p = 0; p < 16; ++p) {
    const int i = p * 256 + tid;
    const int row = i >> 6;
    const int c4 = (i & 63) * 4;
    float4 av = ld4(&tokens[((size_t)(b * M + row)) * D + c4]);
    unsigned a0 = (unsigned)f2bf(av.x) | ((unsigned)f2bf(av.y) << 16);
    unsigned a1 = (unsigned)f2bf(av.z) | ((unsigned)f2bf(av.w) << 16);
    *reinterpret_cast<uint2*>(&At[row * 264 + c4]) = make_uint2(a0, a1);
  }
#pragma unroll
  for (int p = 0; p < 12; ++p) {
    const int u = p * 256 + tid;
    const int row = u >> 5;          // 0..95
    const int c = (u & 31) * 8;
    const int eg = (row < 32) ? (h * 32 + row)
                 : (row < 64) ? (256 + h * 32 + row - 32)
                              : (512 + h * 32 + row - 64);
    *reinterpret_cast<short8*>(&Wq[row * 264 + c]) =
        *reinterpret_cast<const short8*>(&WqkvB[(size_t)eg * 256 + c]);
  }
  float rcp4[4];
#pragma unroll
  for (int r = 0; r < 4; ++r)
    rcp4[r] = 1.0f / denom[b * M + w * 16 + r4 + r];
  __syncthreads();

  // Phase 2: GEMM1 (wave w -> rows w*16..w*16+15, 6 e-tiles)
  floatx4 acc[6] = {{0.f, 0.f, 0.f, 0.f}, {0.f, 0.f, 0.f, 0.f},
                    {0.f, 0.f, 0.f, 0.f}, {0.f, 0.f, 0.f, 0.f},
                    {0.f, 0.f, 0.f, 0.f}, {0.f, 0.f, 0.f, 0.f}};
  const int arow = w * 16 + l15;
#pragma unroll
  for (int ks = 0; ks < 8; ++ks) {
    short8 a = *reinterpret_cast<short8*>(&At[arow * 264 + ks * 32 + q8]);
#pragma unroll
    for (int et = 0; et < 6; ++et) {
      short8 bf = *reinterpret_cast<short8*>(&Wq[(et * 16 + l15) * 264 + ks * 32 + q8]);
      acc[et] = __builtin_amdgcn_mfma_f32_16x16x32_bf16(a, bf, acc[et], 0, 0, 0);
    }
  }
  // preload Wo B-frags for phase 5 (latency hidden under attention)
  short8 wof[4];
#pragma unroll
  for (int dt4 = 0; dt4 < 4; ++dt4)
    wof[dt4] = *reinterpret_cast<const short8*>(
        &WoB[(size_t)(w * 64 + dt4 * 16 + l15) * 256 + h * 32 + q8]);
  __syncthreads();  // all waves done reading At/Wq; overlay region free

  // Phase 3: qkv -> qt/kt/vv (normalized)
#pragma unroll
  for (int r = 0; r < 4; ++r) {
    const int m = w * 16 + r4 + r;
    const float rc = rcp4[r];
#pragma unroll
    for (int et = 0; et < 6; ++et) {
      const float val = acc[et][r] * rc;
      const int c = (et & 1) * 16 + l15;
      if (et < 2) qt[c * 68 + m] = val;
      else if (et < 4) kt[c * 68 + m] = val;
      else vv[m * 36 + c] = val;
    }
  }
  __syncthreads();

  // Phase 4a: S = q.k^T * scale
  {
    const int tm4 = (tid & 15) * 4;
    const int tn4 = (tid >> 4) * 4;
    float sacc[4][4] = {};
    for (int k = 0; k < 32; ++k) {
      float4 a4 = ld4(&qt[k * 68 + tn4]);
      float4 b4 = ld4(&kt[k * 68 + tm4]);
#pragma unroll
      for (int i = 0; i < 4; ++i) {
        const float av = (i == 0) ? a4.x : (i == 1) ? a4.y : (i == 2) ? a4.z : a4.w;
        sacc[i][0] = fmaf(av, b4.x, sacc[i][0]);
        sacc[i][1] = fmaf(av, b4.y, sacc[i][1]);
        sacc[i][2] = fmaf(av, b4.z, sacc[i][2]);
        sacc[i][3] = fmaf(av, b4.w, sacc[i][3]);
      }
    }
    const float scale = 0.17677669529663687f;
#pragma unroll
    for (int i = 0; i < 4; ++i)
      *reinterpret_cast<float4*>(&P[(tn4 + i) * 68 + tm4]) =
          make_float4(sacc[i][0] * scale, sacc[i][1] * scale,
                      sacc[i][2] * scale, sacc[i][3] * scale);
  }
  __syncthreads();
  // Phase 4b: softmax over rows
  if (tid < 64) {
    float mx = -1e30f;
    for (int j = 0; j < 64; ++j) mx = fmaxf(mx, P[tid * 68 + j]);
    float s = 0.0f;
    for (int j = 0; j < 64; ++j) {
      const float e = expf(P[tid * 68 + j] - mx);
      P[tid * 68 + j] = e;
      s += e;
    }
    const float r = 1.0f / s;
    for (int j = 0; j < 64; ++j) P[tid * 68 + j] *= r;
  }
  __syncthreads();
  // Phase 4c: PV -> ao[m][hd]
  if (tid < 128) {
    const int i0 = (tid >> 3) * 4;
    const int c0 = (tid & 7) * 4;
    float o[4][4] = {};
    for (int j = 0; j < 64; ++j) {
      float4 v4 = ld4(&vv[j * 36 + c0]);
#pragma unroll
      for (int ii = 0; ii < 4; ++ii) {
        const float p = P[(i0 + ii) * 68 + j];
        o[ii][0] = fmaf(p, v4.x, o[ii][0]);
        o[ii][1] = fmaf(p, v4.y, o[ii][1]);
        o[ii][2] = fmaf(p, v4.z, o[ii][2]);
        o[ii][3] = fmaf(p, v4.w, o[ii][3]);
      }
    }
#pragma unroll
    for (int ii = 0; ii < 4; ++ii)
#pragma unroll
      for (int jj = 0; jj < 4; ++jj) ao[(i0 + ii) * 36 + c0 + jj] = o[ii][jj];
  }
  __syncthreads();

  // Phase 5: partial out-proj, K=32 (this head's e-slice), wave w -> d-cols w*64..
  floatx4 acc2[4][4] = {{{0.f, 0.f, 0.f, 0.f}, {0.f, 0.f, 0.f, 0.f},
                         {0.f, 0.f, 0.f, 0.f}, {0.f, 0.f, 0.f, 0.f}},
                        {{0.f, 0.f, 0.f, 0.f}, {0.f, 0.f, 0.f, 0.f},
                         {0.f, 0.f, 0.f, 0.f}, {0.f, 0.f, 0.f, 0.f}},
                        {{0.f, 0.f, 0.f, 0.f}, {0.f, 0.f, 0.f, 0.f},
                         {0.f, 0.f, 0.f, 0.f}, {0.f, 0.f, 0.f, 0.f}},
                        {{0.f, 0.f, 0.f, 0.f}, {0.f, 0.f, 0.f, 0.f},
                         {0.f, 0.f, 0.f, 0.f}, {0.f, 0.f, 0.f, 0.f}}};
#pragma unroll
  for (int mt = 0; mt < 4; ++mt) {
    short8 af;
#pragma unroll
    for (int j = 0; j < 8; ++j)
      af[j] = (short)f2bf(ao[(mt * 16 + l15) * 36 + q8 + j]);
#pragma unroll
    for (int dt4 = 0; dt4 < 4; ++dt4)
      acc2[mt][dt4] =
          __builtin_amdgcn_mfma_f32_16x16x32_bf16(af, wof[dt4], acc2[mt][dt4], 0, 0, 0);
  }
#pragma unroll
  for (int mt = 0; mt < 4; ++mt)
#pragma unroll
    for (int dt4 = 0; dt4 < 4; ++dt4)
#pragma unroll
      for (int r = 0; r < 4; ++r) {
        const int m = mt * 16 + r4 + r;
        const int d = w * 64 + dt4 * 16 + l15;
        atomicAdd(&tokO[((size_t)(b * M + m)) * D + d], acc2[mt][dt4][r]);
      }
}

// ---------------------------------------------------------------------------
// K6: out[b,n,d] = sum_m En[b,n,m] * token_out[b,m,d]   (MFMA, K=64)
// Finalize inlined: token_out = (tokO + bo) * rcp(denom) per block into
// TpS[d-local][m]. 128-n tiles, 8 waves. grid (D/64, N/128, B), block 512
__global__ __launch_bounds__(512, 4) void k6_unpool(
    const unsigned short* __restrict__ En, const float* __restrict__ tokO,
    const float* __restrict__ denom, const float* __restrict__ bo,
    float* __restrict__ out) {
  __shared__ unsigned short EnS[128][72];
  __shared__ unsigned short TpS[64][72];
  const int dt = blockIdx.x, nt = blockIdx.y, b = blockIdx.z;
  const int n0 = nt * 128, d0 = dt * 64;
  const int tid = threadIdx.x;
  const int w = tid >> 6, l = tid & 63;
  const int l15 = l & 15;
  const int q8 = (l >> 4) * 8;
  // stage En rows n0..n0+127
#pragma unroll
  for (int p = 0; p < 2; ++p) {
    const int g = p * 512 + tid;
    const int row = g >> 3;
    const int c8 = (g & 7) * 8;
    *reinterpret_cast<short8*>(&EnS[row][c8]) =
        *reinterpret_cast<const short8*>(
            &En[((size_t)(b * N + n0 + row)) * M + c8]);
  }
  // finalize token_out chunk [64 m][64 d] -> TpS[d-local][m] bf16
  {
    const int m = tid >> 3;
    const int c8 = (tid & 7) * 8;
    const float rc = 1.0f / denom[b * M + m];
    const float* tp = &tokO[((size_t)(b * M + m)) * D + d0 + c8];
    float4 v0 = ld4(tp);
    float4 v1 = ld4(tp + 4);
    float4 bb0 = ld4(&bo[d0 + c8]);
    float4 bb1 = ld4(&bo[d0 + c8 + 4]);
    TpS[c8 + 0][m] = f2bf((v0.x + bb0.x) * rc);
    TpS[c8 + 1][m] = f2bf((v0.y + bb0.y) * rc);
    TpS[c8 + 2][m] = f2bf((v0.z + bb0.z) * rc);
    TpS[c8 + 3][m] = f2bf((v0.w + bb0.w) * rc);
    TpS[c8 + 4][m] = f2bf((v1.x + bb1.x) * rc);
    TpS[c8 + 5][m] = f2bf((v1.y + bb1.y) * rc);
    TpS[c8 + 6][m] = f2bf((v1.z + bb1.z) * rc);
    TpS[c8 + 7][m] = f2bf((v1.w + bb1.w) * rc);
  }
  __syncthreads();
  floatx4 acc[4] = {{0.f, 0.f, 0.f, 0.f},
                    {0.f, 0.f, 0.f, 0.f},
                    {0.f, 0.f, 0.f, 0.f},
                    {0.f, 0.f, 0.f, 0.f}};
  const int arow = w * 16 + l15;
#pragma unroll
  for (int ks = 0; ks < 2; ++ks) {
    short8 a = *reinterpret_cast<short8*>(&EnS[arow][ks * 32 + q8]);
#pragma unroll
    for (int dtile = 0; dtile < 4; ++dtile) {
      short8 bf = *reinterpret_cast<short8*>(
          &TpS[dtile * 16 + l15][ks * 32 + q8]);
      acc[dtile] =
          __builtin_amdgcn_mfma_f32_16x16x32_bf16(a, bf, acc[dtile], 0, 0, 0);
    }
  }
#pragma unroll
  for (int dtile = 0; dtile < 4; ++dtile)
#pragma unroll
    for (int r = 0; r < 4; ++r) {
      const int n = n0 + w * 16 + (l >> 4) * 4 + r;
      const int d = d0 + dtile * 16 + l15;
      out[((size_t)(b * N + n)) * D + d] = acc[dtile][r];
    }
}

// ---------------------------------------------------------------------------
extern "C" void kernel_launch(void* const* d_in, const int* in_sizes, int n_in,
                              void* d_out, int out_size, void* d_ws,
                              size_t ws_size, hipStream_t stream) {
  const float* x = (const float*)d_in[0];
  const float* Ws = (const float*)d_in[1];
  const float* bs = (const float*)d_in[2];
  const float* Wqkv = (const float*)d_in[3];
  const float* Wo = (const float*)d_in[4];
  const float* bo = (const float*)d_in[5];
  float* out = (float*)d_out;

  char* p = (char*)d_ws;
  unsigned short* En = (unsigned short*)p;    p += (size_t)B * N * M * 2;       // 8.4 MB
  float* denom = (float*)p;                   p += (size_t)B * M * 4;
  float* tokens = (float*)p;                  p += (size_t)B * M * D * 4;       // 256 KB
  float* tokO = (float*)p;                    p += (size_t)B * M * D * 4;       // 256 KB
  float* tokensP = (float*)p;                 p += (size_t)B * NSLOT * M * D * 4;  // 33.5 MB
  unsigned short* WsB = (unsigned short*)p;   p += (size_t)M * D * 2;           // 32 KB
  unsigned short* WqkvB = (unsigned short*)p; p += (size_t)3 * D * D * 2;       // 384 KB
  unsigned short* WoB = (unsigned short*)p;   p += (size_t)D * D * 2;           // 128 KB

  k0_prep<<<dim3(136), 256, 0, stream>>>(Ws, Wqkv, Wo, WsB, WqkvB, WoB,
                                         denom, tokO);
  k12_fused<<<dim3(N / 128, B), 256, 0, stream>>>(x, WsB, bs, En, denom,
                                                  tokensP);
  k2r_reduce<<<dim3(B * M), 256, 0, stream>>>(tokensP, tokens);
  k_fa<<<dim3(B * H), 256, 0, stream>>>(tokens, WqkvB, WoB, denom, tokO);
  k6_unpool<<<dim3(D / 64, N / 128, B), 512, 0, stream>>>(En, tokO, denom, bo,
                                                          out);
}

// Round 9
// 166.889 us; speedup vs baseline: 1.0566x; 1.0102x over previous
//
#include <hip/hip_runtime.h>
#include <math.h>

constexpr int B = 4;
constexpr int N = 16384;
constexpr int D = 256;
constexpr int M = 64;
constexpr int H = 8;
// HD = 32, 3D = 768
constexpr int NSLOT = 128;  // k12 blocks per batch (N/128)

typedef __attribute__((ext_vector_type(8))) short short8;
typedef __attribute__((ext_vector_type(4))) float floatx4;

__device__ __forceinline__ float4 ld4(const float* p) {
  return *reinterpret_cast<const float4*>(p);
}
__device__ __forceinline__ unsigned short f2bf(float f) {
  unsigned u = __float_as_uint(f);
  unsigned r = (u + 0x7fffu + ((u >> 16) & 1u)) >> 16;  // RNE
  return (unsigned short)r;
}
__device__ __forceinline__ uint2 pack8(float4 a, float4 b, unsigned* hi) {
  unsigned d0 = (unsigned)f2bf(a.x) | ((unsigned)f2bf(a.y) << 16);
  unsigned d1 = (unsigned)f2bf(a.z) | ((unsigned)f2bf(a.w) << 16);
  hi[0] = (unsigned)f2bf(b.x) | ((unsigned)f2bf(b.y) << 16);
  hi[1] = (unsigned)f2bf(b.z) | ((unsigned)f2bf(b.w) << 16);
  return make_uint2(d0, d1);
}

// ---------------------------------------------------------------------------
// K12 (fused logits + exp + En + pooling). Stages Ws (fp32->bf16) itself;
// pool partials -> private tokensP slot (plain stores); denom partials ->
// private denomP slot (plain stores). NO global atomics anywhere.
// grid (N/128, B), block 256 (4 waves).
__global__ __launch_bounds__(256, 2) void k12_fused(
    const float* __restrict__ x, const float* __restrict__ Ws,
    const float* __restrict__ bs, unsigned short* __restrict__ En,
    float* __restrict__ denomP, float* __restrict__ tokensP) {
  __shared__ unsigned short Wt[64][264];   // Ws [m][d] bf16 (33792 B)
  __shared__ unsigned short EsT[64][70];   // E^T [m][n-local] (8960 B)
  __shared__ unsigned short XsT[256][70];  // x^T [d][n-local] (35840 B)
  __shared__ float red[64];
  const int b = blockIdx.y;
  const int nb0 = blockIdx.x * 128;
  const int tid = threadIdx.x;
  const int w = tid >> 6, l = tid & 63;
  const int l15 = l & 15;
  const int q8 = (l >> 4) * 8;
  const int r4 = (l >> 4) * 4;
  const int ar = w * 16 + l15;  // this thread's n-row within 64-subtile

  // issue subtile-0 x loads first (in flight during Wt staging)
  float4 fx0[16];
  {
    const float* xr = &x[((size_t)(b * N + nb0 + ar)) * D];
#pragma unroll
    for (int ks = 0; ks < 8; ++ks) {
      fx0[2 * ks] = ld4(&xr[ks * 32 + q8]);
      fx0[2 * ks + 1] = ld4(&xr[ks * 32 + q8 + 4]);
    }
  }
  // stage Ws fp32 -> Wt bf16 (64 KB L2-hot read, 4 iters x 16 floats/thread)
#pragma unroll
  for (int p = 0; p < 4; ++p) {
    const int i = p * 256 + tid;
    const int row = i >> 4;          // 0..63
    const int c16 = (i & 15) * 16;   // 0..240
    const float* wp = &Ws[(size_t)row * 256 + c16];
    float4 v0 = ld4(wp), v1 = ld4(wp + 4), v2 = ld4(wp + 8), v3 = ld4(wp + 12);
    unsigned hi[2];
    uint2 lo = pack8(v0, v1, hi);
    *reinterpret_cast<uint4*>(&Wt[row][c16]) = make_uint4(lo.x, lo.y, hi[0], hi[1]);
    lo = pack8(v2, v3, hi);
    *reinterpret_cast<uint4*>(&Wt[row][c16 + 8]) = make_uint4(lo.x, lo.y, hi[0], hi[1]);
  }
  if (tid < 64) red[tid] = 0.0f;
  __syncthreads();

  floatx4 acc2[16];
#pragma unroll
  for (int i = 0; i < 16; ++i) acc2[i] = {0.f, 0.f, 0.f, 0.f};

  float4 fx1[16];
  short8 afr0[8], afr1[8];
  floatx4 acc[4];

#define K12_CVT(FX, AFR)                                               \
  do {                                                                 \
    _Pragma("unroll") for (int ks = 0; ks < 8; ++ks) {                 \
      const float4 a0 = FX[2 * ks], a1 = FX[2 * ks + 1];               \
      short8 tt;                                                       \
      tt[0] = (short)f2bf(a0.x); tt[1] = (short)f2bf(a0.y);            \
      tt[2] = (short)f2bf(a0.z); tt[3] = (short)f2bf(a0.w);            \
      tt[4] = (short)f2bf(a1.x); tt[5] = (short)f2bf(a1.y);            \
      tt[6] = (short)f2bf(a1.z); tt[7] = (short)f2bf(a1.w);            \
      AFR[ks] = tt;                                                    \
    }                                                                  \
  } while (0)

#define K12_SCATTER(AFR)                                               \
  do {                                                                 \
    _Pragma("unroll") for (int ks = 0; ks < 8; ++ks)                   \
        _Pragma("unroll") for (int j = 0; j < 8; ++j)                  \
            XsT[ks * 32 + q8 + j][ar] = (unsigned short)AFR[ks][j];    \
  } while (0)

#define K12_LOGITS(AFR)                                                \
  do {                                                                 \
    _Pragma("unroll") for (int i = 0; i < 4; ++i)                      \
        acc[i] = {0.f, 0.f, 0.f, 0.f};                                 \
    _Pragma("unroll") for (int ks = 0; ks < 8; ++ks) {                 \
      _Pragma("unroll") for (int mt = 0; mt < 4; ++mt) {               \
        short8 bf =                                                    \
            *reinterpret_cast<short8*>(&Wt[mt * 16 + l15][ks * 32 + q8]); \
        acc[mt] = __builtin_amdgcn_mfma_f32_16x16x32_bf16(AFR[ks], bf, \
                                                          acc[mt], 0, 0, 0); \
      }                                                                \
    }                                                                  \
  } while (0)

#define K12_EPILOG(N0)                                                 \
  do {                                                                 \
    _Pragma("unroll") for (int mt = 0; mt < 4; ++mt) {                 \
      const int m = mt * 16 + l15;                                     \
      const float bsm = bs[m];                                         \
      float s = 0.0f;                                                  \
      _Pragma("unroll") for (int r = 0; r < 4; ++r) {                  \
        const int n = w * 16 + r4 + r;                                 \
        const float e = __expf(acc[mt][r] + bsm);                      \
        s += e;                                                        \
        const unsigned short eb = f2bf(e);                             \
        EsT[m][w * 16 + r4 + r] = eb;                                  \
        En[((size_t)(b * N + (N0) + n)) * M + m] = eb;                 \
      }                                                                \
      atomicAdd(&red[m], s);                                           \
    }                                                                  \
  } while (0)

#define K12_POOL()                                                     \
  do {                                                                 \
    _Pragma("unroll") for (int ks2 = 0; ks2 < 2; ++ks2) {              \
      const int nf = ks2 * 32 + q8;                                    \
      short8 a = *reinterpret_cast<short8*>(&EsT[w * 16 + l15][nf]);   \
      _Pragma("unroll") for (int dt4 = 0; dt4 < 16; ++dt4) {           \
        short8 bf = *reinterpret_cast<short8*>(&XsT[dt4 * 16 + l15][nf]); \
        acc2[dt4] = __builtin_amdgcn_mfma_f32_16x16x32_bf16(a, bf,     \
                                                            acc2[dt4], 0, 0, 0); \
      }                                                                \
    }                                                                  \
  } while (0)

  // ---- subtile 0 ----
  K12_CVT(fx0, afr0);
  {  // prefetch subtile 1 (hidden under subtile-0 compute)
    const float* xr = &x[((size_t)(b * N + nb0 + 64 + ar)) * D];
#pragma unroll
    for (int ks = 0; ks < 8; ++ks) {
      fx1[2 * ks] = ld4(&xr[ks * 32 + q8]);
      fx1[2 * ks + 1] = ld4(&xr[ks * 32 + q8 + 4]);
    }
  }
  K12_SCATTER(afr0);   // ds_writes overlap the MFMAs below
  K12_LOGITS(afr0);
  K12_EPILOG(nb0);
  K12_CVT(fx1, afr1);  // register-only; hoisted above the barrier
  __syncthreads();     // XsT/EsT staged by all waves
  K12_POOL();
  __syncthreads();     // pool reads done; safe to overwrite XsT/EsT

  // ---- subtile 1 ----
  K12_SCATTER(afr1);
  K12_LOGITS(afr1);
  K12_EPILOG(nb0 + 64);
  __syncthreads();
  K12_POOL();

  // ---- flush: plain stores into this block's private slots ----
  if (tid < 64)
    denomP[((size_t)(b * NSLOT) + blockIdx.x) * M + tid] = red[tid];
  float* op = tokensP + ((size_t)(b * NSLOT + blockIdx.x) * M) * D;
#pragma unroll
  for (int dt4 = 0; dt4 < 16; ++dt4)
#pragma unroll
    for (int r = 0; r < 4; ++r)
      op[(w * 16 + r4 + r) * D + dt4 * 16 + l15] = acc2[dt4][r];
#undef K12_CVT
#undef K12_SCATTER
#undef K12_LOGITS
#undef K12_EPILOG
#undef K12_POOL
}

// ---------------------------------------------------------------------------
// K2R: tokensB[b][m][d] (bf16) = f2bf(sum_s tokensP[b][s][m][d]);
// rdenom[b][m] = 1 / sum_s denomP[b][s][m]; zero tokO.
// grid (B*M) = 256 blocks, block 256 (thread = one d). Coalesced reads.
__global__ __launch_bounds__(256) void k2r_reduce(
    const float* __restrict__ tokensP, const float* __restrict__ denomP,
    unsigned short* __restrict__ tokensB, float* __restrict__ rdenom,
    float* __restrict__ tokO) {
  const int b = blockIdx.x >> 6;
  const int m = blockIdx.x & 63;
  const int d = threadIdx.x;
  // zero tokO (256 blocks x 256 threads covers 65536 exactly)
  tokO[(size_t)blockIdx.x * 256 + d] = 0.0f;
  const float* base = tokensP + ((size_t)(b * NSLOT) * M + m) * D + d;
  float s0 = 0.f, s1 = 0.f, s2 = 0.f, s3 = 0.f;
#pragma unroll 4
  for (int s = 0; s < NSLOT; s += 4) {
    s0 += base[(size_t)(s + 0) * M * D];
    s1 += base[(size_t)(s + 1) * M * D];
    s2 += base[(size_t)(s + 2) * M * D];
    s3 += base[(size_t)(s + 3) * M * D];
  }
  tokensB[((size_t)(b * M) + m) * D + d] = f2bf((s0 + s1) + (s2 + s3));
  // denom: wave 0 reduces 128 slot partials
  if (d < 64) {
    float v = denomP[((size_t)(b * NSLOT) + d) * M + m] +
              denomP[((size_t)(b * NSLOT) + 64 + d) * M + m];
#pragma unroll
    for (int off = 32; off > 0; off >>= 1) v += __shfl_down(v, off);
    if (d == 0) rdenom[b * M + m] = 1.0f / v;
  }
}

// ---------------------------------------------------------------------------
// K_FA: fused token stage, one block per (b,h), 256 threads. Converts its
// own Wqkv/Wo slices from fp32 inline (no k0). Reads tokensB bf16 + rdenom.
// grid (B*H), block 256
__global__ __launch_bounds__(256) void k_fa(
    const unsigned short* __restrict__ tokensB, const float* __restrict__ Wqkv,
    const float* __restrict__ Wo, const float* __restrict__ rdenom,
    float* __restrict__ tokO) {
  __shared__ __align__(16) char smem[84480];
  unsigned short* const At = reinterpret_cast<unsigned short*>(smem);          // [64][264]
  unsigned short* const Wq = reinterpret_cast<unsigned short*>(smem + 33792);  // [96][264]
  float* const qt = reinterpret_cast<float*>(smem);            // [32][68]
  float* const kt = reinterpret_cast<float*>(smem + 8704);     // [32][68]
  float* const vv = reinterpret_cast<float*>(smem + 17408);    // [64][36]
  float* const P  = reinterpret_cast<float*>(smem + 26624);    // [64][68]
  float* const ao = reinterpret_cast<float*>(smem + 44032);    // [64][36]
  const int b = blockIdx.x >> 3;
  const int h = blockIdx.x & 7;
  const int tid = threadIdx.x;
  const int w = tid >> 6, l = tid & 63;
  const int l15 = l & 15;
  const int q8 = (l >> 4) * 8;
  const int r4 = (l >> 4) * 4;

  // Phase 1: stage At (bf16 copy) + Wq (fp32 -> bf16 cvt)
#pragma unroll
  for (int p = 0; p < 8; ++p) {
    const int u = p * 256 + tid;
    const int row = u >> 5;          // 0..63
    const int c = (u & 31) * 8;
    *reinterpret_cast<short8*>(&At[row * 264 + c]) =
        *reinterpret_cast<const short8*>(&tokensB[((size_t)(b * M + row)) * 256 + c]);
  }
#pragma unroll
  for (int p = 0; p < 6; ++p) {
    const int u = p * 256 + tid;
    const int row = u >> 4;          // 0..95
    const int c16 = (u & 15) * 16;
    const int eg = (row < 32) ? (h * 32 + row)
                 : (row < 64) ? (256 + h * 32 + row - 32)
                              : (512 + h * 32 + row - 64);
    const float* wp = &Wqkv[(size_t)eg * 256 + c16];
    float4 v0 = ld4(wp), v1 = ld4(wp + 4), v2 = ld4(wp + 8), v3 = ld4(wp + 12);
    unsigned hi[2];
    uint2 lo = pack8(v0, v1, hi);
    *reinterpret_cast<uint4*>(&Wq[row * 264 + c16]) =
        make_uint4(lo.x, lo.y, hi[0], hi[1]);
    lo = pack8(v2, v3, hi);
    *reinterpret_cast<uint4*>(&Wq[row * 264 + c16 + 8]) =
        make_uint4(lo.x, lo.y, hi[0], hi[1]);
  }
  float rcp4[4];
#pragma unroll
  for (int r = 0; r < 4; ++r)
    rcp4[r] = rdenom[b * M + w * 16 + r4 + r];
  __syncthreads();

  // Phase 2: GEMM1 (wave w -> rows w*16..w*16+15, 6 e-tiles)
  floatx4 acc[6] = {{0.f, 0.f, 0.f, 0.f}, {0.f, 0.f, 0.f, 0.f},
                    {0.f, 0.f, 0.f, 0.f}, {0.f, 0.f, 0.f, 0.f},
                    {0.f, 0.f, 0.f, 0.f}, {0.f, 0.f, 0.f, 0.f}};
  const int arow = w * 16 + l15;
#pragma unroll
  for (int ks = 0; ks < 8; ++ks) {
    short8 a = *reinterpret_cast<short8*>(&At[arow * 264 + ks * 32 + q8]);
#pragma unroll
    for (int et = 0; et < 6; ++et) {
      short8 bf = *reinterpret_cast<short8*>(&Wq[(et * 16 + l15) * 264 + ks * 32 + q8]);
      acc[et] = __builtin_amdgcn_mfma_f32_16x16x32_bf16(a, bf, acc[et], 0, 0, 0);
    }
  }
  // preload + convert Wo B-frags for phase 5 (latency hidden under attention)
  short8 wof[4];
#pragma unroll
  for (int dt4 = 0; dt4 < 4; ++dt4) {
    const float* wp = &Wo[(size_t)(w * 64 + dt4 * 16 + l15) * 256 + h * 32 + q8];
    float4 v0 = ld4(wp), v1 = ld4(wp + 4);
    short8 tt;
    tt[0] = (short)f2bf(v0.x); tt[1] = (short)f2bf(v0.y);
    tt[2] = (short)f2bf(v0.z); tt[3] = (short)f2bf(v0.w);
    tt[4] = (short)f2bf(v1.x); tt[5] = (short)f2bf(v1.y);
    tt[6] = (short)f2bf(v1.z); tt[7] = (short)f2bf(v1.w);
    wof[dt4] = tt;
  }
  __syncthreads();  // all waves done reading At/Wq; overlay region free

  // Phase 3: qkv -> qt/kt/vv (normalized)
#pragma unroll
  for (int r = 0; r < 4; ++r) {
    const int m = w * 16 + r4 + r;
    const float rc = rcp4[r];
#pragma unroll
    for (int et = 0; et < 6; ++et) {
      const float val = acc[et][r] * rc;
      const int c = (et & 1) * 16 + l15;
      if (et < 2) qt[c * 68 + m] = val;
      else if (et < 4) kt[c * 68 + m] = val;
      else vv[m * 36 + c] = val;
    }
  }
  __syncthreads();

  // Phase 4a: S = q.k^T * scale
  {
    const int tm4 = (tid & 15) * 4;
    const int tn4 = (tid >> 4) * 4;
    float sacc[4][4] = {};
    for (int k = 0; k < 32; ++k) {
      float4 a4 = ld4(&qt[k * 68 + tn4]);
      float4 b4 = ld4(&kt[k * 68 + tm4]);
#pragma unroll
      for (int i = 0; i < 4; ++i) {
        const float av = (i == 0) ? a4.x : (i == 1) ? a4.y : (i == 2) ? a4.z : a4.w;
        sacc[i][0] = fmaf(av, b4.x, sacc[i][0]);
        sacc[i][1] = fmaf(av, b4.y, sacc[i][1]);
        sacc[i][2] = fmaf(av, b4.z, sacc[i][2]);
        sacc[i][3] = fmaf(av, b4.w, sacc[i][3]);
      }
    }
    const float scale = 0.17677669529663687f;
#pragma unroll
    for (int i = 0; i < 4; ++i)
      *reinterpret_cast<float4*>(&P[(tn4 + i) * 68 + tm4]) =
          make_float4(sacc[i][0] * scale, sacc[i][1] * scale,
                      sacc[i][2] * scale, sacc[i][3] * scale);
  }
  __syncthreads();
  // Phase 4b: softmax over rows
  if (tid < 64) {
    float mx = -1e30f;
    for (int j = 0; j < 64; ++j) mx = fmaxf(mx, P[tid * 68 + j]);
    float s = 0.0f;
    for (int j = 0; j < 64; ++j) {
      const float e = expf(P[tid * 68 + j] - mx);
      P[tid * 68 + j] = e;
      s += e;
    }
    const float r = 1.0f / s;
    for (int j = 0; j < 64; ++j) P[tid * 68 + j] *= r;
  }
  __syncthreads();
  // Phase 4c: PV -> ao[m][hd]
  if (tid < 128) {
    const int i0 = (tid >> 3) * 4;
    const int c0 = (tid & 7) * 4;
    float o[4][4] = {};
    for (int j = 0; j < 64; ++j) {
      float4 v4 = ld4(&vv[j * 36 + c0]);
#pragma unroll
      for (int ii = 0; ii < 4; ++ii) {
        const float p = P[(i0 + ii) * 68 + j];
        o[ii][0] = fmaf(p, v4.x, o[ii][0]);
        o[ii][1] = fmaf(p, v4.y, o[ii][1]);
        o[ii][2] = fmaf(p, v4.z, o[ii][2]);
        o[ii][3] = fmaf(p, v4.w, o[ii][3]);
      }
    }
#pragma unroll
    for (int ii = 0; ii < 4; ++ii)
#pragma unroll
      for (int jj = 0; jj < 4; ++jj) ao[(i0 + ii) * 36 + c0 + jj] = o[ii][jj];
  }
  __syncthreads();

  // Phase 5: partial out-proj, K=32 (this head's e-slice), wave w -> d-cols w*64..
  floatx4 acc2[4][4] = {{{0.f, 0.f, 0.f, 0.f}, {0.f, 0.f, 0.f, 0.f},
                         {0.f, 0.f, 0.f, 0.f}, {0.f, 0.f, 0.f, 0.f}},
                        {{0.f, 0.f, 0.f, 0.f}, {0.f, 0.f, 0.f, 0.f},
                         {0.f, 0.f, 0.f, 0.f}, {0.f, 0.f, 0.f, 0.f}},
                        {{0.f, 0.f, 0.f, 0.f}, {0.f, 0.f, 0.f, 0.f},
                         {0.f, 0.f, 0.f, 0.f}, {0.f, 0.f, 0.f, 0.f}},
                        {{0.f, 0.f, 0.f, 0.f}, {0.f, 0.f, 0.f, 0.f},
                         {0.f, 0.f, 0.f, 0.f}, {0.f, 0.f, 0.f, 0.f}}};
#pragma unroll
  for (int mt = 0; mt < 4; ++mt) {
    short8 af;
#pragma unroll
    for (int j = 0; j < 8; ++j)
      af[j] = (short)f2bf(ao[(mt * 16 + l15) * 36 + q8 + j]);
#pragma unroll
    for (int dt4 = 0; dt4 < 4; ++dt4)
      acc2[mt][dt4] =
          __builtin_amdgcn_mfma_f32_16x16x32_bf16(af, wof[dt4], acc2[mt][dt4], 0, 0, 0);
  }
#pragma unroll
  for (int mt = 0; mt < 4; ++mt)
#pragma unroll
    for (int dt4 = 0; dt4 < 4; ++dt4)
#pragma unroll
      for (int r = 0; r < 4; ++r) {
        const int m = mt * 16 + r4 + r;
        const int d = w * 64 + dt4 * 16 + l15;
        atomicAdd(&tokO[((size_t)(b * M + m)) * D + d], acc2[mt][dt4][r]);
      }
}

// ---------------------------------------------------------------------------
// K6: out[b,n,d] = sum_m En[b,n,m] * token_out[b,m,d]   (MFMA, K=64)
// Finalize inlined (token_out = (tokO + bo) * rdenom). 256-n tiles, 2 passes.
// grid (D/64, N/256, B), block 512
__global__ __launch_bounds__(512, 4) void k6_unpool(
    const unsigned short* __restrict__ En, const float* __restrict__ tokO,
    const float* __restrict__ rdenom, const float* __restrict__ bo,
    float* __restrict__ out) {
  __shared__ unsigned short EnS[256][72];
  __shared__ unsigned short TpS[64][72];
  const int dt = blockIdx.x, nt = blockIdx.y, b = blockIdx.z;
  const int n0 = nt * 256, d0 = dt * 64;
  const int tid = threadIdx.x;
  const int w = tid >> 6, l = tid & 63;
  const int l15 = l & 15;
  const int q8 = (l >> 4) * 8;
  // stage En rows n0..n0+255
#pragma unroll
  for (int p = 0; p < 4; ++p) {
    const int g = p * 512 + tid;
    const int row = g >> 3;
    const int c8 = (g & 7) * 8;
    *reinterpret_cast<short8*>(&EnS[row][c8]) =
        *reinterpret_cast<const short8*>(
            &En[((size_t)(b * N + n0 + row)) * M + c8]);
  }
  // finalize token_out chunk [64 m][64 d] -> TpS[d-local][m] bf16
  {
    const int m = tid >> 3;
    const int c8 = (tid & 7) * 8;
    const float rc = rdenom[b * M + m];
    const float* tp = &tokO[((size_t)(b * M + m)) * D + d0 + c8];
    float4 v0 = ld4(tp);
    float4 v1 = ld4(tp + 4);
    float4 bb0 = ld4(&bo[d0 + c8]);
    float4 bb1 = ld4(&bo[d0 + c8 + 4]);
    TpS[c8 + 0][m] = f2bf((v0.x + bb0.x) * rc);
    TpS[c8 + 1][m] = f2bf((v0.y + bb0.y) * rc);
    TpS[c8 + 2][m] = f2bf((v0.z + bb0.z) * rc);
    TpS[c8 + 3][m] = f2bf((v0.w + bb0.w) * rc);
    TpS[c8 + 4][m] = f2bf((v1.x + bb1.x) * rc);
    TpS[c8 + 5][m] = f2bf((v1.y + bb1.y) * rc);
    TpS[c8 + 6][m] = f2bf((v1.z + bb1.z) * rc);
    TpS[c8 + 7][m] = f2bf((v1.w + bb1.w) * rc);
  }
  __syncthreads();
#pragma unroll
  for (int pass = 0; pass < 2; ++pass) {
    const int arow = pass * 128 + w * 16 + l15;
    floatx4 acc[4] = {{0.f, 0.f, 0.f, 0.f},
                      {0.f, 0.f, 0.f, 0.f},
                      {0.f, 0.f, 0.f, 0.f},
                      {0.f, 0.f, 0.f, 0.f}};
#pragma unroll
    for (int ks = 0; ks < 2; ++ks) {
      short8 a = *reinterpret_cast<short8*>(&EnS[arow][ks * 32 + q8]);
#pragma unroll
      for (int dtile = 0; dtile < 4; ++dtile) {
        short8 bf = *reinterpret_cast<short8*>(
            &TpS[dtile * 16 + l15][ks * 32 + q8]);
        acc[dtile] =
            __builtin_amdgcn_mfma_f32_16x16x32_bf16(a, bf, acc[dtile], 0, 0, 0);
      }
    }
#pragma unroll
    for (int dtile = 0; dtile < 4; ++dtile)
#pragma unroll
      for (int r = 0; r < 4; ++r) {
        const int n = n0 + pass * 128 + w * 16 + (l >> 4) * 4 + r;
        const int d = d0 + dtile * 16 + l15;
        out[((size_t)(b * N + n)) * D + d] = acc[dtile][r];
      }
  }
}

// ---------------------------------------------------------------------------
extern "C" void kernel_launch(void* const* d_in, const int* in_sizes, int n_in,
                              void* d_out, int out_size, void* d_ws,
                              size_t ws_size, hipStream_t stream) {
  const float* x = (const float*)d_in[0];
  const float* Ws = (const float*)d_in[1];
  const float* bs = (const float*)d_in[2];
  const float* Wqkv = (const float*)d_in[3];
  const float* Wo = (const float*)d_in[4];
  const float* bo = (const float*)d_in[5];
  float* out = (float*)d_out;

  char* p = (char*)d_ws;
  unsigned short* En = (unsigned short*)p;  p += (size_t)B * N * M * 2;          // 8.4 MB
  float* tokensP = (float*)p;               p += (size_t)B * NSLOT * M * D * 4;  // 33.5 MB
  float* denomP = (float*)p;                p += (size_t)B * NSLOT * M * 4;      // 128 KB
  float* rdenom = (float*)p;                p += (size_t)B * M * 4;              // 1 KB
  unsigned short* tokensB = (unsigned short*)p; p += (size_t)B * M * D * 2;      // 128 KB
  float* tokO = (float*)p;                  p += (size_t)B * M * D * 4;          // 256 KB

  k12_fused<<<dim3(N / 128, B), 256, 0, stream>>>(x, Ws, bs, En, denomP,
                                                  tokensP);
  k2r_reduce<<<dim3(B * M), 256, 0, stream>>>(tokensP, denomP, tokensB,
                                              rdenom, tokO);
  k_fa<<<dim3(B * H), 256, 0, stream>>>(tokensB, Wqkv, Wo, rdenom, tokO);
  k6_unpool<<<dim3(D / 64, N / 256, B), 512, 0, stream>>>(En, tokO, rdenom, bo,
                                                          out);
}

// Round 10
// 163.323 us; speedup vs baseline: 1.0797x; 1.0218x over previous
//
#include <hip/hip_runtime.h>
#include <math.h>

constexpr int B = 4;
constexpr int N = 16384;
constexpr int D = 256;
constexpr int M = 64;
constexpr int H = 8;
// HD = 32, 3D = 768
constexpr int NSLOT = 64;  // k12 blocks per batch (N/256)

typedef __attribute__((ext_vector_type(8))) short short8;
typedef __attribute__((ext_vector_type(4))) float floatx4;

__device__ __forceinline__ float4 ld4(const float* p) {
  return *reinterpret_cast<const float4*>(p);
}
__device__ __forceinline__ unsigned short f2bf(float f) {
  unsigned u = __float_as_uint(f);
  unsigned r = (u + 0x7fffu + ((u >> 16) & 1u)) >> 16;  // RNE
  return (unsigned short)r;
}
__device__ __forceinline__ uint2 pack8(float4 a, float4 b, unsigned* hi) {
  unsigned d0 = (unsigned)f2bf(a.x) | ((unsigned)f2bf(a.y) << 16);
  unsigned d1 = (unsigned)f2bf(a.z) | ((unsigned)f2bf(a.w) << 16);
  hi[0] = (unsigned)f2bf(b.x) | ((unsigned)f2bf(b.y) << 16);
  hi[1] = (unsigned)f2bf(b.z) | ((unsigned)f2bf(b.w) << 16);
  return make_uint2(d0, d1);
}

// ---------------------------------------------------------------------------
// K12: producer-consumer wave-specialized fused logits+exp+En+pooling.
// 1 block/CU (grid 64x4), 512 threads. Waves 0-3 (producers): per 64-n
// subtile load x -> cvt -> scatter XsT[buf] -> logits MFMA -> exp ->
// EsT[buf]/En/red, with next subtile's loads always in flight. Waves 4-7
// (consumers): pool-MFMA the previous subtile's buffers CONCURRENTLY
// (double-buffered -> 1 barrier/subtile), accumulate across 4 subtiles,
// flush to private tokensP slot. No global atomics.
__global__ __launch_bounds__(512, 2) void k12_fused(
    const float* __restrict__ x, const float* __restrict__ Ws,
    const float* __restrict__ bs, unsigned short* __restrict__ En,
    float* __restrict__ denomP, float* __restrict__ tokensP) {
  __shared__ unsigned short Wt[64][264];      // Ws bf16 (33792 B)
  __shared__ unsigned short EsT[2][64][70];   // E^T dbuf (2x8960 B)
  __shared__ unsigned short XsT[2][256][70];  // x^T dbuf (2x35840 B)
  __shared__ float red[64];
  const int b = blockIdx.y;
  const int nb0 = blockIdx.x * 256;
  const int tid = threadIdx.x;
  const int w = tid >> 6, l = tid & 63;
  const int l15 = l & 15;
  const int q8 = (l >> 4) * 8;
  const int r4 = (l >> 4) * 4;
  const bool prod = (w < 4);
  const int pw = w & 3;            // producer row-group / consumer m-group
  const int ar = pw * 16 + l15;    // n-row within subtile (producers)

  float4 fxA[16], fxB[16];
  short8 afr[8];
  floatx4 acc[4];

  // prologue: producers issue subtile-0 loads
  if (prod) {
    const float* xr = &x[((size_t)(b * N + nb0 + ar)) * D];
#pragma unroll
    for (int ks = 0; ks < 8; ++ks) {
      fxA[2 * ks] = ld4(&xr[ks * 32 + q8]);
      fxA[2 * ks + 1] = ld4(&xr[ks * 32 + q8 + 4]);
    }
  }
  // all 8 waves stage Ws fp32 -> bf16
#pragma unroll
  for (int p = 0; p < 2; ++p) {
    const int i = p * 512 + tid;
    const int row = i >> 4;
    const int c16 = (i & 15) * 16;
    const float* wp = &Ws[(size_t)row * 256 + c16];
    float4 v0 = ld4(wp), v1 = ld4(wp + 4), v2 = ld4(wp + 8), v3 = ld4(wp + 12);
    unsigned hi[2];
    uint2 lo = pack8(v0, v1, hi);
    *reinterpret_cast<uint4*>(&Wt[row][c16]) = make_uint4(lo.x, lo.y, hi[0], hi[1]);
    lo = pack8(v2, v3, hi);
    *reinterpret_cast<uint4*>(&Wt[row][c16 + 8]) = make_uint4(lo.x, lo.y, hi[0], hi[1]);
  }
  if (tid < 64) red[tid] = 0.0f;
  __syncthreads();

  floatx4 acc2[16];
#pragma unroll
  for (int i = 0; i < 16; ++i) acc2[i] = {0.f, 0.f, 0.f, 0.f};

#define K12_CVT(FX)                                                    \
  do {                                                                 \
    _Pragma("unroll") for (int ks = 0; ks < 8; ++ks) {                 \
      const float4 a0 = FX[2 * ks], a1 = FX[2 * ks + 1];               \
      short8 tt;                                                       \
      tt[0] = (short)f2bf(a0.x); tt[1] = (short)f2bf(a0.y);            \
      tt[2] = (short)f2bf(a0.z); tt[3] = (short)f2bf(a0.w);            \
      tt[4] = (short)f2bf(a1.x); tt[5] = (short)f2bf(a1.y);            \
      tt[6] = (short)f2bf(a1.z); tt[7] = (short)f2bf(a1.w);            \
      afr[ks] = tt;                                                    \
    }                                                                  \
  } while (0)

#define K12_PREF(FX, NOFF)                                             \
  do {                                                                 \
    const float* xr = &x[((size_t)(b * N + (NOFF) + ar)) * D];         \
    _Pragma("unroll") for (int ks = 0; ks < 8; ++ks) {                 \
      FX[2 * ks] = ld4(&xr[ks * 32 + q8]);                             \
      FX[2 * ks + 1] = ld4(&xr[ks * 32 + q8 + 4]);                     \
    }                                                                  \
  } while (0)

#define K12_SCATTER(BUF)                                               \
  do {                                                                 \
    _Pragma("unroll") for (int ks = 0; ks < 8; ++ks)                   \
        _Pragma("unroll") for (int j = 0; j < 8; ++j)                  \
            XsT[BUF][ks * 32 + q8 + j][ar] = (unsigned short)afr[ks][j]; \
  } while (0)

#define K12_LOGITS()                                                   \
  do {                                                                 \
    _Pragma("unroll") for (int i = 0; i < 4; ++i)                      \
        acc[i] = {0.f, 0.f, 0.f, 0.f};                                 \
    _Pragma("unroll") for (int ks = 0; ks < 8; ++ks) {                 \
      _Pragma("unroll") for (int mt = 0; mt < 4; ++mt) {               \
        short8 bf =                                                    \
            *reinterpret_cast<short8*>(&Wt[mt * 16 + l15][ks * 32 + q8]); \
        acc[mt] = __builtin_amdgcn_mfma_f32_16x16x32_bf16(afr[ks], bf, \
                                                          acc[mt], 0, 0, 0); \
      }                                                                \
    }                                                                  \
  } while (0)

#define K12_EPILOG(N0, BUF)                                            \
  do {                                                                 \
    _Pragma("unroll") for (int mt = 0; mt < 4; ++mt) {                 \
      const int m = mt * 16 + l15;                                     \
      const float bsm = bs[m];                                         \
      float s = 0.0f;                                                  \
      _Pragma("unroll") for (int r = 0; r < 4; ++r) {                  \
        const int n = pw * 16 + r4 + r;                                \
        const float e = __expf(acc[mt][r] + bsm);                      \
        s += e;                                                        \
        const unsigned short eb = f2bf(e);                             \
        EsT[BUF][m][pw * 16 + r4 + r] = eb;                            \
        En[((size_t)(b * N + (N0) + n)) * M + m] = eb;                 \
      }                                                                \
      atomicAdd(&red[m], s);                                           \
    }                                                                  \
  } while (0)

#define K12_POOL(BUF)                                                  \
  do {                                                                 \
    _Pragma("unroll") for (int ks2 = 0; ks2 < 2; ++ks2) {              \
      const int nf = ks2 * 32 + q8;                                    \
      short8 a = *reinterpret_cast<short8*>(&EsT[BUF][pw * 16 + l15][nf]); \
      _Pragma("unroll") for (int dt4 = 0; dt4 < 16; ++dt4) {           \
        short8 bf = *reinterpret_cast<short8*>(&XsT[BUF][dt4 * 16 + l15][nf]); \
        acc2[dt4] = __builtin_amdgcn_mfma_f32_16x16x32_bf16(a, bf,     \
                                                            acc2[dt4], 0, 0, 0); \
      }                                                                \
    }                                                                  \
  } while (0)

  // ---- t = 0 ----
  if (prod) {
    K12_CVT(fxA);
    K12_PREF(fxB, nb0 + 64);
    K12_SCATTER(0);
    K12_LOGITS();
    K12_EPILOG(nb0, 0);
  }
  __syncthreads();
  // ---- t = 1 ----
  if (prod) {
    K12_CVT(fxB);
    K12_PREF(fxA, nb0 + 128);
    K12_SCATTER(1);
    K12_LOGITS();
    K12_EPILOG(nb0 + 64, 1);
  } else {
    K12_POOL(0);
  }
  __syncthreads();
  // ---- t = 2 ----
  if (prod) {
    K12_CVT(fxA);
    K12_PREF(fxB, nb0 + 192);
    K12_SCATTER(0);
    K12_LOGITS();
    K12_EPILOG(nb0 + 128, 0);
  } else {
    K12_POOL(1);
  }
  __syncthreads();
  // ---- t = 3 ----
  if (prod) {
    K12_CVT(fxB);
    K12_SCATTER(1);
    K12_LOGITS();
    K12_EPILOG(nb0 + 192, 1);
  } else {
    K12_POOL(0);
  }
  __syncthreads();
  // ---- drain ----
  if (!prod) K12_POOL(1);

  // ---- flush ----
  if (tid < 64)
    denomP[((size_t)(b * NSLOT) + blockIdx.x) * M + tid] = red[tid];
  if (!prod) {
    float* op = tokensP + ((size_t)(b * NSLOT + blockIdx.x) * M) * D;
#pragma unroll
    for (int dt4 = 0; dt4 < 16; ++dt4)
#pragma unroll
      for (int r = 0; r < 4; ++r)
        op[(pw * 16 + r4 + r) * D + dt4 * 16 + l15] = acc2[dt4][r];
  }
#undef K12_CVT
#undef K12_PREF
#undef K12_SCATTER
#undef K12_LOGITS
#undef K12_EPILOG
#undef K12_POOL
}

// ---------------------------------------------------------------------------
// K2R: tokensB[b][m][d] (bf16) = f2bf(sum_s tokensP[b][s][m][d]);
// rdenom[b][m] = 1 / sum_s denomP[b][s][m]; zero tokO.
// grid (B*M) = 256 blocks, block 256 (thread = one d). Coalesced reads.
__global__ __launch_bounds__(256) void k2r_reduce(
    const float* __restrict__ tokensP, const float* __restrict__ denomP,
    unsigned short* __restrict__ tokensB, float* __restrict__ rdenom,
    float* __restrict__ tokO) {
  const int b = blockIdx.x >> 6;
  const int m = blockIdx.x & 63;
  const int d = threadIdx.x;
  // zero tokO (256 blocks x 256 threads covers 65536 exactly)
  tokO[(size_t)blockIdx.x * 256 + d] = 0.0f;
  const float* base = tokensP + ((size_t)(b * NSLOT) * M + m) * D + d;
  float s0 = 0.f, s1 = 0.f, s2 = 0.f, s3 = 0.f;
#pragma unroll 4
  for (int s = 0; s < NSLOT; s += 4) {
    s0 += base[(size_t)(s + 0) * M * D];
    s1 += base[(size_t)(s + 1) * M * D];
    s2 += base[(size_t)(s + 2) * M * D];
    s3 += base[(size_t)(s + 3) * M * D];
  }
  tokensB[((size_t)(b * M) + m) * D + d] = f2bf((s0 + s1) + (s2 + s3));
  // denom: wave 0 reduces 64 slot partials
  if (d < 64) {
    float v = denomP[((size_t)(b * NSLOT) + d) * M + m];
#pragma unroll
    for (int off = 32; off > 0; off >>= 1) v += __shfl_down(v, off);
    if (d == 0) rdenom[b * M + m] = 1.0f / v;
  }
}

// ---------------------------------------------------------------------------
// K_FA: fused token stage, one block per (b,h), 256 threads. Converts its
// own Wqkv/Wo slices from fp32 inline. Reads tokensB bf16 + rdenom.
// grid (B*H), block 256
__global__ __launch_bounds__(256) void k_fa(
    const unsigned short* __restrict__ tokensB, const float* __restrict__ Wqkv,
    const float* __restrict__ Wo, const float* __restrict__ rdenom,
    float* __restrict__ tokO) {
  __shared__ __align__(16) char smem[84480];
  unsigned short* const At = reinterpret_cast<unsigned short*>(smem);          // [64][264]
  unsigned short* const Wq = reinterpret_cast<unsigned short*>(smem + 33792);  // [96][264]
  float* const qt = reinterpret_cast<float*>(smem);            // [32][68]
  float* const kt = reinterpret_cast<float*>(smem + 8704);     // [32][68]
  float* const vv = reinterpret_cast<float*>(smem + 17408);    // [64][36]
  float* const P  = reinterpret_cast<float*>(smem + 26624);    // [64][68]
  float* const ao = reinterpret_cast<float*>(smem + 44032);    // [64][36]
  const int b = blockIdx.x >> 3;
  const int h = blockIdx.x & 7;
  const int tid = threadIdx.x;
  const int w = tid >> 6, l = tid & 63;
  const int l15 = l & 15;
  const int q8 = (l >> 4) * 8;
  const int r4 = (l >> 4) * 4;

  // Phase 1: stage At (bf16 copy) + Wq (fp32 -> bf16 cvt)
#pragma unroll
  for (int p = 0; p < 8; ++p) {
    const int u = p * 256 + tid;
    const int row = u >> 5;          // 0..63
    const int c = (u & 31) * 8;
    *reinterpret_cast<short8*>(&At[row * 264 + c]) =
        *reinterpret_cast<const short8*>(&tokensB[((size_t)(b * M + row)) * 256 + c]);
  }
#pragma unroll
  for (int p = 0; p < 6; ++p) {
    const int u = p * 256 + tid;
    const int row = u >> 4;          // 0..95
    const int c16 = (u & 15) * 16;
    const int eg = (row < 32) ? (h * 32 + row)
                 : (row < 64) ? (256 + h * 32 + row - 32)
                              : (512 + h * 32 + row - 64);
    const float* wp = &Wqkv[(size_t)eg * 256 + c16];
    float4 v0 = ld4(wp), v1 = ld4(wp + 4), v2 = ld4(wp + 8), v3 = ld4(wp + 12);
    unsigned hi[2];
    uint2 lo = pack8(v0, v1, hi);
    *reinterpret_cast<uint4*>(&Wq[row * 264 + c16]) =
        make_uint4(lo.x, lo.y, hi[0], hi[1]);
    lo = pack8(v2, v3, hi);
    *reinterpret_cast<uint4*>(&Wq[row * 264 + c16 + 8]) =
        make_uint4(lo.x, lo.y, hi[0], hi[1]);
  }
  float rcp4[4];
#pragma unroll
  for (int r = 0; r < 4; ++r)
    rcp4[r] = rdenom[b * M + w * 16 + r4 + r];
  __syncthreads();

  // Phase 2: GEMM1 (wave w -> rows w*16..w*16+15, 6 e-tiles)
  floatx4 acc[6] = {{0.f, 0.f, 0.f, 0.f}, {0.f, 0.f, 0.f, 0.f},
                    {0.f, 0.f, 0.f, 0.f}, {0.f, 0.f, 0.f, 0.f},
                    {0.f, 0.f, 0.f, 0.f}, {0.f, 0.f, 0.f, 0.f}};
  const int arow = w * 16 + l15;
#pragma unroll
  for (int ks = 0; ks < 8; ++ks) {
    short8 a = *reinterpret_cast<short8*>(&At[arow * 264 + ks * 32 + q8]);
#pragma unroll
    for (int et = 0; et < 6; ++et) {
      short8 bf = *reinterpret_cast<short8*>(&Wq[(et * 16 + l15) * 264 + ks * 32 + q8]);
      acc[et] = __builtin_amdgcn_mfma_f32_16x16x32_bf16(a, bf, acc[et], 0, 0, 0);
    }
  }
  // preload + convert Wo B-frags for phase 5 (latency hidden under attention)
  short8 wof[4];
#pragma unroll
  for (int dt4 = 0; dt4 < 4; ++dt4) {
    const float* wp = &Wo[(size_t)(w * 64 + dt4 * 16 + l15) * 256 + h * 32 + q8];
    float4 v0 = ld4(wp), v1 = ld4(wp + 4);
    short8 tt;
    tt[0] = (short)f2bf(v0.x); tt[1] = (short)f2bf(v0.y);
    tt[2] = (short)f2bf(v0.z); tt[3] = (short)f2bf(v0.w);
    tt[4] = (short)f2bf(v1.x); tt[5] = (short)f2bf(v1.y);
    tt[6] = (short)f2bf(v1.z); tt[7] = (short)f2bf(v1.w);
    wof[dt4] = tt;
  }
  __syncthreads();  // all waves done reading At/Wq; overlay region free

  // Phase 3: qkv -> qt/kt/vv (normalized)
#pragma unroll
  for (int r = 0; r < 4; ++r) {
    const int m = w * 16 + r4 + r;
    const float rc = rcp4[r];
#pragma unroll
    for (int et = 0; et < 6; ++et) {
      const float val = acc[et][r] * rc;
      const int c = (et & 1) * 16 + l15;
      if (et < 2) qt[c * 68 + m] = val;
      else if (et < 4) kt[c * 68 + m] = val;
      else vv[m * 36 + c] = val;
    }
  }
  __syncthreads();

  // Phase 4a: S = q.k^T * scale
  {
    const int tm4 = (tid & 15) * 4;
    const int tn4 = (tid >> 4) * 4;
    float sacc[4][4] = {};
    for (int k = 0; k < 32; ++k) {
      float4 a4 = ld4(&qt[k * 68 + tn4]);
      float4 b4 = ld4(&kt[k * 68 + tm4]);
#pragma unroll
      for (int i = 0; i < 4; ++i) {
        const float av = (i == 0) ? a4.x : (i == 1) ? a4.y : (i == 2) ? a4.z : a4.w;
        sacc[i][0] = fmaf(av, b4.x, sacc[i][0]);
        sacc[i][1] = fmaf(av, b4.y, sacc[i][1]);
        sacc[i][2] = fmaf(av, b4.z, sacc[i][2]);
        sacc[i][3] = fmaf(av, b4.w, sacc[i][3]);
      }
    }
    const float scale = 0.17677669529663687f;
#pragma unroll
    for (int i = 0; i < 4; ++i)
      *reinterpret_cast<float4*>(&P[(tn4 + i) * 68 + tm4]) =
          make_float4(sacc[i][0] * scale, sacc[i][1] * scale,
                      sacc[i][2] * scale, sacc[i][3] * scale);
  }
  __syncthreads();
  // Phase 4b: softmax over rows
  if (tid < 64) {
    float mx = -1e30f;
    for (int j = 0; j < 64; ++j) mx = fmaxf(mx, P[tid * 68 + j]);
    float s = 0.0f;
    for (int j = 0; j < 64; ++j) {
      const float e = expf(P[tid * 68 + j] - mx);
      P[tid * 68 + j] = e;
      s += e;
    }
    const float r = 1.0f / s;
    for (int j = 0; j < 64; ++j) P[tid * 68 + j] *= r;
  }
  __syncthreads();
  // Phase 4c: PV -> ao[m][hd]
  if (tid < 128) {
    const int i0 = (tid >> 3) * 4;
    const int c0 = (tid & 7) * 4;
    float o[4][4] = {};
    for (int j = 0; j < 64; ++j) {
      float4 v4 = ld4(&vv[j * 36 + c0]);
#pragma unroll
      for (int ii = 0; ii < 4; ++ii) {
        const float p = P[(i0 + ii) * 68 + j];
        o[ii][0] = fmaf(p, v4.x, o[ii][0]);
        o[ii][1] = fmaf(p, v4.y, o[ii][1]);
        o[ii][2] = fmaf(p, v4.z, o[ii][2]);
        o[ii][3] = fmaf(p, v4.w, o[ii][3]);
      }
    }
#pragma unroll
    for (int ii = 0; ii < 4; ++ii)
#pragma unroll
      for (int jj = 0; jj < 4; ++jj) ao[(i0 + ii) * 36 + c0 + jj] = o[ii][jj];
  }
  __syncthreads();

  // Phase 5: partial out-proj, K=32 (this head's e-slice), wave w -> d-cols w*64..
  floatx4 acc2[4][4] = {{{0.f, 0.f, 0.f, 0.f}, {0.f, 0.f, 0.f, 0.f},
                         {0.f, 0.f, 0.f, 0.f}, {0.f, 0.f, 0.f, 0.f}},
                        {{0.f, 0.f, 0.f, 0.f}, {0.f, 0.f, 0.f, 0.f},
                         {0.f, 0.f, 0.f, 0.f}, {0.f, 0.f, 0.f, 0.f}},
                        {{0.f, 0.f, 0.f, 0.f}, {0.f, 0.f, 0.f, 0.f},
                         {0.f, 0.f, 0.f, 0.f}, {0.f, 0.f, 0.f, 0.f}},
                        {{0.f, 0.f, 0.f, 0.f}, {0.f, 0.f, 0.f, 0.f},
                         {0.f, 0.f, 0.f, 0.f}, {0.f, 0.f, 0.f, 0.f}}};
#pragma unroll
  for (int mt = 0; mt < 4; ++mt) {
    short8 af;
#pragma unroll
    for (int j = 0; j < 8; ++j)
      af[j] = (short)f2bf(ao[(mt * 16 + l15) * 36 + q8 + j]);
#pragma unroll
    for (int dt4 = 0; dt4 < 4; ++dt4)
      acc2[mt][dt4] =
          __builtin_amdgcn_mfma_f32_16x16x32_bf16(af, wof[dt4], acc2[mt][dt4], 0, 0, 0);
  }
#pragma unroll
  for (int mt = 0; mt < 4; ++mt)
#pragma unroll
    for (int dt4 = 0; dt4 < 4; ++dt4)
#pragma unroll
      for (int r = 0; r < 4; ++r) {
        const int m = mt * 16 + r4 + r;
        const int d = w * 64 + dt4 * 16 + l15;
        atomicAdd(&tokO[((size_t)(b * M + m)) * D + d], acc2[mt][dt4][r]);
      }
}

// ---------------------------------------------------------------------------
// K6: out[b,n,d] = sum_m En[b,n,m] * token_out[b,m,d]   (MFMA, K=64)
// Finalize inlined (token_out = (tokO + bo) * rdenom). 256-n tiles, 2 passes.
// grid (D/64, N/256, B), block 512
__global__ __launch_bounds__(512, 4) void k6_unpool(
    const unsigned short* __restrict__ En, const float* __restrict__ tokO,
    const float* __restrict__ rdenom, const float* __restrict__ bo,
    float* __restrict__ out) {
  __shared__ unsigned short EnS[256][72];
  __shared__ unsigned short TpS[64][72];
  const int dt = blockIdx.x, nt = blockIdx.y, b = blockIdx.z;
  const int n0 = nt * 256, d0 = dt * 64;
  const int tid = threadIdx.x;
  const int w = tid >> 6, l = tid & 63;
  const int l15 = l & 15;
  const int q8 = (l >> 4) * 8;
  // stage En rows n0..n0+255
#pragma unroll
  for (int p = 0; p < 4; ++p) {
    const int g = p * 512 + tid;
    const int row = g >> 3;
    const int c8 = (g & 7) * 8;
    *reinterpret_cast<short8*>(&EnS[row][c8]) =
        *reinterpret_cast<const short8*>(
            &En[((size_t)(b * N + n0 + row)) * M + c8]);
  }
  // finalize token_out chunk [64 m][64 d] -> TpS[d-local][m] bf16
  {
    const int m = tid >> 3;
    const int c8 = (tid & 7) * 8;
    const float rc = rdenom[b * M + m];
    const float* tp = &tokO[((size_t)(b * M + m)) * D + d0 + c8];
    float4 v0 = ld4(tp);
    float4 v1 = ld4(tp + 4);
    float4 bb0 = ld4(&bo[d0 + c8]);
    float4 bb1 = ld4(&bo[d0 + c8 + 4]);
    TpS[c8 + 0][m] = f2bf((v0.x + bb0.x) * rc);
    TpS[c8 + 1][m] = f2bf((v0.y + bb0.y) * rc);
    TpS[c8 + 2][m] = f2bf((v0.z + bb0.z) * rc);
    TpS[c8 + 3][m] = f2bf((v0.w + bb0.w) * rc);
    TpS[c8 + 4][m] = f2bf((v1.x + bb1.x) * rc);
    TpS[c8 + 5][m] = f2bf((v1.y + bb1.y) * rc);
    TpS[c8 + 6][m] = f2bf((v1.z + bb1.z) * rc);
    TpS[c8 + 7][m] = f2bf((v1.w + bb1.w) * rc);
  }
  __syncthreads();
#pragma unroll
  for (int pass = 0; pass < 2; ++pass) {
    const int arow = pass * 128 + w * 16 + l15;
    floatx4 acc[4] = {{0.f, 0.f, 0.f, 0.f},
                      {0.f, 0.f, 0.f, 0.f},
                      {0.f, 0.f, 0.f, 0.f},
                      {0.f, 0.f, 0.f, 0.f}};
#pragma unroll
    for (int ks = 0; ks < 2; ++ks) {
      short8 a = *reinterpret_cast<short8*>(&EnS[arow][ks * 32 + q8]);
#pragma unroll
      for (int dtile = 0; dtile < 4; ++dtile) {
        short8 bf = *reinterpret_cast<short8*>(
            &TpS[dtile * 16 + l15][ks * 32 + q8]);
        acc[dtile] =
            __builtin_amdgcn_mfma_f32_16x16x32_bf16(a, bf, acc[dtile], 0, 0, 0);
      }
    }
#pragma unroll
    for (int dtile = 0; dtile < 4; ++dtile)
#pragma unroll
      for (int r = 0; r < 4; ++r) {
        const int n = n0 + pass * 128 + w * 16 + (l >> 4) * 4 + r;
        const int d = d0 + dtile * 16 + l15;
        out[((size_t)(b * N + n)) * D + d] = acc[dtile][r];
      }
  }
}

// ---------------------------------------------------------------------------
extern "C" void kernel_launch(void* const* d_in, const int* in_sizes, int n_in,
                              void* d_out, int out_size, void* d_ws,
                              size_t ws_size, hipStream_t stream) {
  const float* x = (const float*)d_in[0];
  const float* Ws = (const float*)d_in[1];
  const float* bs = (const float*)d_in[2];
  const float* Wqkv = (const float*)d_in[3];
  const float* Wo = (const float*)d_in[4];
  const float* bo = (const float*)d_in[5];
  float* out = (float*)d_out;

  char* p = (char*)d_ws;
  unsigned short* En = (unsigned short*)p;  p += (size_t)B * N * M * 2;          // 8.4 MB
  float* tokensP = (float*)p;               p += (size_t)B * NSLOT * M * D * 4;  // 16.8 MB
  float* denomP = (float*)p;                p += (size_t)B * NSLOT * M * 4;      // 64 KB
  float* rdenom = (float*)p;                p += (size_t)B * M * 4;              // 1 KB
  unsigned short* tokensB = (unsigned short*)p; p += (size_t)B * M * D * 2;      // 128 KB
  float* tokO = (float*)p;                  p += (size_t)B * M * D * 4;          // 256 KB

  k12_fused<<<dim3(N / 256, B), 512, 0, stream>>>(x, Ws, bs, En, denomP,
                                                  tokensP);
  k2r_reduce<<<dim3(B * M), 256, 0, stream>>>(tokensP, denomP, tokensB,
                                              rdenom, tokO);
  k_fa<<<dim3(B * H), 256, 0, stream>>>(tokensB, Wqkv, Wo, rdenom, tokO);
  k6_unpool<<<dim3(D / 64, N / 256, B), 512, 0, stream>>>(En, tokO, rdenom, bo,
                                                          out);
}